// Round 4
// baseline (1294.675 us; speedup 1.0000x reference)
//
#include <hip/hip_runtime.h>

// ---------------------------------------------------------------------------
// SentenceDecoder on MI355X — f32 I/O, bf16 MFMA internals.
// Dims: B=64, T=32, P=64, E=H=512, V=30000, IN=1568, rows = T*B = 2048.
// Output (flat f32): logp [64][32][30000] | attn [64][32][65] | slp [64]
// ---------------------------------------------------------------------------

typedef unsigned short bf16u;
typedef __attribute__((ext_vector_type(8))) short short8;   // MFMA A/B frag
typedef __attribute__((ext_vector_type(4))) float floatx4;  // MFMA C/D frag

#define DEV __device__ __forceinline__

DEV float b2f(bf16u u) { return __uint_as_float(((unsigned)u) << 16); }
DEV bf16u f2b(float f) {
  unsigned u = __float_as_uint(f);
  u = (u + 0x7fffu + ((u >> 16) & 1u)) >> 16;   // RNE
  return (bf16u)u;
}

// fast tanh: 1 - 2/(1+exp(2x)).  exp->inf => 1; exp->0 => -1.  ~5 instrs.
DEV float ftanh(float x) {
  float e = __expf(2.0f * x);
  float r = __builtin_amdgcn_rcpf(e + 1.0f);
  return __builtin_fmaf(-2.0f, r, 1.0f);
}
DEV float fsigm(float x) {
  return __builtin_amdgcn_rcpf(1.0f + __expf(-x));
}

// ---------------------------------------------------------------------------
// f32 -> bf16 conversion
// ---------------------------------------------------------------------------
__global__ __launch_bounds__(256)
void cvt_kernel(const float* __restrict__ src, bf16u* __restrict__ dst, int n)
{
  int i = blockIdx.x * 256 + threadIdx.x;
  if (i < n) dst[i] = f2b(src[i]);
}

// ---------------------------------------------------------------------------
// image mean over P=64 (f32)
// ---------------------------------------------------------------------------
__global__ __launch_bounds__(256)
void mean_kernel(const float* __restrict__ image, float* __restrict__ imean)
{
  int b = blockIdx.x;
  for (int e = threadIdx.x; e < 512; e += 256) {
    float s = 0.f;
    for (int p = 0; p < 64; ++p) s += image[(size_t)(b * 64 + p) * 512 + e];
    imean[b * 512 + e] = s * (1.0f / 64.0f);
  }
}

// ---------------------------------------------------------------------------
// X[t*64+b] (bf16) = [imean | vp | label | topic | emb[tok]]  width 1568
// ---------------------------------------------------------------------------
__global__ __launch_bounds__(256)
void prep_kernel(const float* __restrict__ imean, const float* __restrict__ vp,
                 const float* __restrict__ lab, const float* __restrict__ topic,
                 const int* __restrict__ text, const float* __restrict__ wemb,
                 bf16u* __restrict__ X)
{
  int b = blockIdx.x;
  for (int t = 0; t < 32; ++t) {
    bf16u* xr = X + ((size_t)t * 64 + b) * 1568;
    int tok = (t == 0) ? 0 : text[b * 32 + t - 1];
    for (int e = threadIdx.x; e < 512; e += 256) {
      xr[e] = f2b(imean[b * 512 + e]);
      xr[544 + e] = f2b(topic[b * 512 + e]);
      xr[1056 + e] = f2b(wemb[(size_t)tok * 512 + e]);
    }
    if (threadIdx.x < 16) {
      xr[512 + threadIdx.x] = f2b(vp[b * 16 + threadIdx.x]);
      xr[528 + threadIdx.x] = f2b(lab[b * 16 + threadIdx.x]);
    }
  }
}

// ---------------------------------------------------------------------------
// pack w_hh [2048][512] f32 -> bf16 wpack[blk][kg][rr][8]
// blk = (row&511)>>4, lc = row&15, gate = row>>9, rr = gate*16+lc, kg = k>>3
// ---------------------------------------------------------------------------
__global__ __launch_bounds__(256)
void pack_whh(const float* __restrict__ whh, bf16u* __restrict__ wpack)
{
  int idx = blockIdx.x * 256 + threadIdx.x;   // 2048*512
  int gr = idx >> 9, k = idx & 511;
  int gate = gr >> 9, win = gr & 511;
  int blk = win >> 4, lc = win & 15;
  int rr = gate * 16 + lc;
  wpack[(size_t)blk * 32768 + (((k >> 3) * 64 + rr) << 3) + (k & 7)] =
      f2b(whh[(size_t)gr * 512 + k]);
}

// ---------------------------------------------------------------------------
// MFMA GEMM (m97 pattern): C[m,n] = act( A[m,:].W[n,:] + bias1 (+bias2) )
// A: M x K bf16 (lda), W: N x K bf16 (ldw).  128x128 tile, BK=32, 2x2 waves.
// MODE 1: vocab epilogue, 1-D grid of 3760 blocks with XCD-chunked swizzle:
//         xcd = blk&7 owns runs of 16 slots -> one n-tile's 16 m-tiles stay
//         on one XCD (W panel fetched once per XCD L2, reused 16x).
// MODE 2: bf16 store to C, legacy 2-D grid (x = n-tile, y = m-tile).
// ---------------------------------------------------------------------------
#define BK 32
#define LDT 40

template<int MODE>
__global__ __launch_bounds__(256)
void gemm_bt(const bf16u* __restrict__ A, int lda,
             const bf16u* __restrict__ W, int ldw,
             const float* __restrict__ bias1, const float* __restrict__ bias2,
             bf16u* __restrict__ C, int ldc,
             int M, int N, int K, int act,
             const float* __restrict__ temp,
             float* __restrict__ outbase,
             float* __restrict__ pmax, float* __restrict__ psum)
{
  __shared__ __align__(16) bf16u As[128 * LDT];
  __shared__ __align__(16) bf16u Ws[128 * LDT];
  const int tid = threadIdx.x;
  int m0, n0, ntile = 0;
  if (MODE == 1) {
    // 3760 blocks; xcd p&7, slot p>>3 (0..469).  16 consecutive slots on one
    // xcd -> one n-tile.  slots<464: nt=(slot>>4)*8+xcd covers nt 0..231;
    // tail 6 slots x 8 xcds = 48 blocks cover nt 232..234.
    int p = blockIdx.x;
    int xcd = p & 7, slot = p >> 3;
    int nt, mt;
    if (slot < 464) { nt = (slot >> 4) * 8 + xcd; mt = slot & 15; }
    else { int idx = (slot - 464) * 8 + xcd; nt = 232 + (idx >> 4); mt = idx & 15; }
    m0 = mt * 128; n0 = nt * 128; ntile = nt;
  } else {
    n0 = blockIdx.x * 128;
    m0 = blockIdx.y * 128;
  }
  const int wave = tid >> 6, lane = tid & 63;
  const int wm = wave >> 1, wn = wave & 1;
  const int q = lane >> 4, l16 = lane & 15;
  const int r0 = tid >> 2, s0 = tid & 3;

  const floatx4 zero = {0.f, 0.f, 0.f, 0.f};
  floatx4 acc[4][4];
#pragma unroll
  for (int i = 0; i < 4; ++i)
#pragma unroll
    for (int j = 0; j < 4; ++j) acc[i][j] = zero;

  int ar0 = m0 + r0;      if (ar0 >= M) ar0 = M - 1;
  int ar1 = m0 + r0 + 64; if (ar1 >= M) ar1 = M - 1;
  int wr0 = n0 + r0;      if (wr0 >= N) wr0 = N - 1;
  int wr1 = n0 + r0 + 64; if (wr1 >= N) wr1 = N - 1;
  const bf16u* Ap0 = A + (size_t)ar0 * lda + s0 * 8;
  const bf16u* Ap1 = A + (size_t)ar1 * lda + s0 * 8;
  const bf16u* Wp0 = W + (size_t)wr0 * ldw + s0 * 8;
  const bf16u* Wp1 = W + (size_t)wr1 * ldw + s0 * 8;

  for (int k0 = 0; k0 < K; k0 += BK) {
    const int4 a0 = *(const int4*)(Ap0 + k0);
    const int4 a1 = *(const int4*)(Ap1 + k0);
    const int4 w0 = *(const int4*)(Wp0 + k0);
    const int4 w1 = *(const int4*)(Wp1 + k0);
    __syncthreads();
    *(int4*)(As + r0 * LDT + s0 * 8) = a0;
    *(int4*)(As + (r0 + 64) * LDT + s0 * 8) = a1;
    *(int4*)(Ws + r0 * LDT + s0 * 8) = w0;
    *(int4*)(Ws + (r0 + 64) * LDT + s0 * 8) = w1;
    __syncthreads();
    short8 af[4], wf[4];
#pragma unroll
    for (int i = 0; i < 4; ++i) {
      af[i] = *(const short8*)(As + (wm * 64 + i * 16 + l16) * LDT + q * 8);
      wf[i] = *(const short8*)(Ws + (wn * 64 + i * 16 + l16) * LDT + q * 8);
    }
#pragma unroll
    for (int i = 0; i < 4; ++i)
#pragma unroll
      for (int j = 0; j < 4; ++j)
        acc[i][j] = __builtin_amdgcn_mfma_f32_16x16x32_bf16(af[i], wf[j], acc[i][j], 0, 0, 0);
  }

  // C/D layout: col = lane&15, row = (lane>>4)*4 + reg
  int colb[4]; float bias[4];
#pragma unroll
  for (int j = 0; j < 4; ++j) {
    int col = n0 + wn * 64 + j * 16 + l16;
    colb[j] = col;
    int cc = col < N ? col : N - 1;
    float bv = 0.f;
    if (bias1) bv += bias1[cc];
    if (bias2) bv += bias2[cc];
    bias[j] = bv;
  }

  if (MODE == 2) {
#pragma unroll
    for (int i = 0; i < 4; ++i) {
#pragma unroll
      for (int r = 0; r < 4; ++r) {
        int row = m0 + wm * 64 + i * 16 + q * 4 + r;
        if (row < M) {
#pragma unroll
          for (int j = 0; j < 4; ++j) {
            int col = colb[j];
            if (col < N) {
              float v = acc[i][j][r] + bias[j];
              if (act == 1) v = fmaxf(v, 0.f);
              C[(size_t)row * ldc + col] = f2b(v);
            }
          }
        }
      }
    }
  } else {   // MODE 1: vocab
    int pc = ntile * 2 + wn;   // 64-col slice (< 470)
#pragma unroll
    for (int i = 0; i < 4; ++i) {
#pragma unroll
      for (int r = 0; r < 4; ++r) {
        int row = m0 + wm * 64 + i * 16 + q * 4 + r;   // t*64 + b
        int bb = row & 63, tt = row >> 6;
        float rt = 1.0f / temp[bb];
        float vals[4];
#pragma unroll
        for (int j = 0; j < 4; ++j) {
          int col = colb[j];
          float v = (acc[i][j][r] + bias[j]) * rt;
          if (col < N) {
            outbase[(size_t)bb * 960000 + (size_t)tt * 30000 + col] = v;
            vals[j] = v;
          } else vals[j] = -1e30f;
        }
        float mx = fmaxf(fmaxf(vals[0], vals[1]), fmaxf(vals[2], vals[3]));
#pragma unroll
        for (int off = 1; off < 16; off <<= 1) mx = fmaxf(mx, __shfl_xor(mx, off));
        float s = 0.f;
#pragma unroll
        for (int j = 0; j < 4; ++j)
          s += (vals[j] > -1e29f) ? __expf(vals[j] - mx) : 0.f;
#pragma unroll
        for (int off = 1; off < 16; off <<= 1) s += __shfl_xor(s, off);
        if (l16 == 0) {
          pmax[(size_t)row * 470 + pc] = mx;
          psum[(size_t)row * 470 + pc] = s;
        }
      }
    }
  }
}

// ---------------------------------------------------------------------------
// scalar f32 GEMM for tiny h0/m0 (M=64)
// ---------------------------------------------------------------------------
template<int ROWS>
__global__ void gemm_tmpl(const float* __restrict__ A, int lda,
                          const float* __restrict__ W, int ldw,
                          const float* __restrict__ bias1,
                          float* __restrict__ C, int ldc,
                          int M, int N, int K, int act)
{
  constexpr int RP = ROWS + 4;
  extern __shared__ __align__(16) float Ash[];
  const int tid = threadIdx.x;
  const int m0 = blockIdx.y * ROWS;
  const int n0 = blockIdx.x * 256;
  for (int idx = tid; idx < ROWS * K; idx += 256) {
    int r = idx / K, k = idx - r * K;
    int rr = m0 + r; if (rr >= M) rr = M - 1;
    Ash[k * RP + r] = A[(size_t)rr * lda + k];
  }
  __syncthreads();
  int n = n0 + tid;
  if (n >= N) return;
  float acc[ROWS];
#pragma unroll
  for (int r = 0; r < ROWS; ++r) acc[r] = 0.f;
  const float* wr = W + (size_t)n * ldw;
  for (int k = 0; k < K; ++k) {
    float w = wr[k];
    const float* a = Ash + (size_t)k * RP;
#pragma unroll
    for (int r = 0; r < ROWS; ++r) acc[r] += w * a[r];
  }
  float bv = bias1 ? bias1[n] : 0.f;
#pragma unroll
  for (int r = 0; r < ROWS; ++r) {
    int row = m0 + r;
    if (row < M) {
      float v = acc[r] + bv;
      if (act == 1) v = fmaxf(v, 0.f);
      else if (act == 2) v = tanhf(v);
      C[(size_t)row * ldc + n] = v;
    }
  }
}

// ---------------------------------------------------------------------------
// init LSTM state: pack h0 (f32) into packed bf16 layout; zero grid barrier
// packed pos for h[b][jj]: ((jj>>3)*64 + b)*8 + (jj&7)
// ---------------------------------------------------------------------------
__global__ __launch_bounds__(256)
void init_state(const float* __restrict__ h0b, bf16u* __restrict__ hOut,
                unsigned* __restrict__ bar)
{
  int i = blockIdx.x * 256 + threadIdx.x;   // 32768
  int b = i >> 9, jj = i & 511;
  hOut[(((jj >> 3) * 64 + b) << 3) + (jj & 7)] = f2b(h0b[i]);
  if (i < 2)
    __hip_atomic_store(bar + i, 0u, __ATOMIC_RELAXED, __HIP_MEMORY_SCOPE_AGENT);
}

// ---------------------------------------------------------------------------
// device-scope grid barrier for 32 co-resident blocks.
// bar[0] = arrival count, bar[1] = generation.
// ---------------------------------------------------------------------------
DEV void gbar(unsigned* bar, int tid)
{
  __syncthreads();
  if (tid == 0) {
    __threadfence();   // release: publish this block's global writes
    unsigned gen = __hip_atomic_load(bar + 1, __ATOMIC_RELAXED, __HIP_MEMORY_SCOPE_AGENT);
    unsigned prev = __hip_atomic_fetch_add(bar, 1u, __ATOMIC_ACQ_REL, __HIP_MEMORY_SCOPE_AGENT);
    if (prev == 31u) {
      __hip_atomic_store(bar, 0u, __ATOMIC_RELAXED, __HIP_MEMORY_SCOPE_AGENT);
      __hip_atomic_fetch_add(bar + 1, 1u, __ATOMIC_RELEASE, __HIP_MEMORY_SCOPE_AGENT);
    } else {
      while (__hip_atomic_load(bar + 1, __ATOMIC_ACQUIRE, __HIP_MEMORY_SCOPE_AGENT) == gen)
        __builtin_amdgcn_s_sleep(2);
    }
    __threadfence();   // acquire: invalidate caches before next step's reads
  }
  __syncthreads();
}

// ---------------------------------------------------------------------------
// persistent LSTM: 32 blocks, one launch for all 32 timesteps.
// Weights staged to LDS ONCE; m-state in registers; h exchanged via global
// (double-buffered hA/hB) with a device-scope grid barrier per step.
// LDS: weights 64KB + h 64KB + gates 16.6KB = 147,712 B (1 block/CU).
// ---------------------------------------------------------------------------
__global__ __launch_bounds__(256)
void lstm_all(const bf16u* __restrict__ wpack, const bf16u* __restrict__ gx,
              bf16u* __restrict__ hA, bf16u* __restrict__ hB,
              const float* __restrict__ m0b, bf16u* __restrict__ h_all,
              unsigned* __restrict__ bar)
{
  extern __shared__ __align__(16) char smem[];
  bf16u* wsh = (bf16u*)smem;                 // 32768 bf16, [kg][rr][8] (once)
  bf16u* hsh = (bf16u*)(smem + 65536);       // 32768 bf16, [kg][b][8] (per step)
  float* gsh = (float*)(smem + 131072);      // [64][65]
  const int blk = blockIdx.x, tid = threadIdx.x;

  {  // stage weight slice once
    const int4* wsrc = (const int4*)(wpack + (size_t)blk * 32768);
    int4* wdst = (int4*)wsh;
#pragma unroll
    for (int u = 0; u < 16; ++u) wdst[tid + 256 * u] = wsrc[tid + 256 * u];
  }

  // m-state in registers: u -> (b = (tid+256u)>>4, lc = (tid+256u)&15)
  float mreg[4];
#pragma unroll
  for (int u = 0; u < 4; ++u) {
    int p = tid + 256 * u;
    mreg[u] = m0b[(p >> 4) * 512 + blk * 16 + (p & 15)];
  }

  const int wave = tid >> 6, lane = tid & 63;
  const int wm = wave >> 1, wn = wave & 1, q = lane >> 4, l16 = lane & 15;
  const floatx4 zero = {0.f, 0.f, 0.f, 0.f};

  for (int t = 0; t < 32; ++t) {
    const bf16u* hIn = (t & 1) ? hB : hA;
    bf16u* hOut = (t & 1) ? hA : hB;

    {  // stage h (64 KB, same source for all blocks)
      const int4* hsrc = (const int4*)hIn;
      int4* hdst = (int4*)hsh;
#pragma unroll
      for (int u = 0; u < 16; ++u) hdst[tid + 256 * u] = hsrc[tid + 256 * u];
    }
    __syncthreads();

    floatx4 acc[2][2];
#pragma unroll
    for (int i = 0; i < 2; ++i)
#pragma unroll
      for (int j = 0; j < 2; ++j) acc[i][j] = zero;

    for (int s = 0; s < 16; ++s) {
      short8 af[2], wf[2];
#pragma unroll
      for (int i = 0; i < 2; ++i)
        af[i] = *(const short8*)(hsh + ((((s * 4 + q) * 64) + wm * 32 + i * 16 + l16) << 3));
#pragma unroll
      for (int j = 0; j < 2; ++j)
        wf[j] = *(const short8*)(wsh + ((((s * 4 + q) * 64) + wn * 32 + j * 16 + l16) << 3));
#pragma unroll
      for (int i = 0; i < 2; ++i)
#pragma unroll
        for (int j = 0; j < 2; ++j)
          acc[i][j] = __builtin_amdgcn_mfma_f32_16x16x32_bf16(af[i], wf[j], acc[i][j], 0, 0, 0);
    }
    // D: col(rr) = lane&15 (+tile), row(b) = q*4+reg (+tile)
#pragma unroll
    for (int i = 0; i < 2; ++i)
#pragma unroll
      for (int j = 0; j < 2; ++j)
#pragma unroll
        for (int r = 0; r < 4; ++r)
          gsh[(wn * 32 + j * 16 + l16) * 65 + (wm * 32 + i * 16 + q * 4 + r)] = acc[i][j][r];
    __syncthreads();

#pragma unroll
    for (int u = 0; u < 4; ++u) {
      int p = tid + 256 * u;            // 1024 pairs
      int b = p >> 4, lc = p & 15;
      int jj = blk * 16 + lc;
      const bf16u* gxr = gx + ((size_t)t * 64 + b) * 2048;
      float ai = gsh[(lc) * 65 + b]        + b2f(gxr[jj]);
      float af = gsh[(16 + lc) * 65 + b]   + b2f(gxr[512 + jj]);
      float ag = gsh[(32 + lc) * 65 + b]   + b2f(gxr[1024 + jj]);
      float ao = gsh[(48 + lc) * 65 + b]   + b2f(gxr[1536 + jj]);
      float iv = fsigm(ai);
      float fv = fsigm(af);
      float gv = ftanh(ag);
      float ov = fsigm(ao);
      float mm = fv * mreg[u] + iv * gv;
      float hn = ov * ftanh(mm);
      mreg[u] = mm;
      bf16u hb = f2b(hn);
      hOut[(((jj >> 3) * 64 + b) << 3) + (jj & 7)] = hb;
      h_all[((size_t)t * 64 + b) * 512 + jj] = hb;
    }
    gbar(bar, tid);   // publish hOut; next step reads it as hIn
  }
}

// ---------------------------------------------------------------------------
// attention per (t,b) row — wave w owns k-quarter, lane l owns p = l.
// ---------------------------------------------------------------------------
__global__ __launch_bounds__(256)
void attn_kernel(const bf16u* __restrict__ vbuf, const float* __restrict__ image,
                 const bf16u* __restrict__ hs_bf, const bf16u* __restrict__ hh2,
                 const bf16u* __restrict__ s2, const float* __restrict__ wz,
                 const float* __restrict__ zb, float* __restrict__ attn_out,
                 bf16u* __restrict__ ctx)
{
  const int rown = blockIdx.x;            // t*64 + b
  const int bb = rown & 63, tt = rown >> 6;
  const int tid = threadIdx.x;
  const int wave = tid >> 6, lane = tid & 63;

  __shared__ float2 hwz[512];        // (hh, wz) per k
  __shared__ float zpart[64][4];     // per-p per-wave z partials
  __shared__ float spart[4];         // s-row per-wave partials
  __shared__ float ash[66];
  __shared__ float4 cpart[128];

  float sv0, sv1;
  {
    unsigned hr = *(const unsigned*)(hh2 + (size_t)rown * 512 + tid * 2);
    unsigned sr = *(const unsigned*)(s2 + (size_t)rown * 512 + tid * 2);
    float2 w2 = *(const float2*)(wz + tid * 2);
    hwz[tid * 2]     = make_float2(b2f((bf16u)(hr & 0xffffu)), w2.x);
    hwz[tid * 2 + 1] = make_float2(b2f((bf16u)(hr >> 16)), w2.y);
    sv0 = b2f((bf16u)(sr & 0xffffu));
    sv1 = b2f((bf16u)(sr >> 16));
  }
  __syncthreads();

  {
    const bf16u* vrow = vbuf + (size_t)(bb * 64 + lane) * 512 + wave * 128;
    float acc = 0.f;
    for (int c = 0; c < 16; ++c) {
      short8 vv = *(const short8*)(vrow + c * 8);
#pragma unroll
      for (int e = 0; e < 8; ++e) {
        float2 hz = hwz[wave * 128 + c * 8 + e];   // wave-uniform -> broadcast
        float tn = ftanh(b2f((bf16u)vv[e]) + hz.x);
        acc = __builtin_fmaf(tn, hz.y, acc);
      }
    }
    zpart[lane][wave] = acc;
  }

  {
    float2 h0 = hwz[tid * 2], h1 = hwz[tid * 2 + 1];
    float sacc = ftanh(sv0 + h0.x) * h0.y + ftanh(sv1 + h1.x) * h1.y;
#pragma unroll
    for (int off = 1; off < 64; off <<= 1) sacc += __shfl_xor(sacc, off);
    if (lane == 0) spart[wave] = sacc;
  }
  __syncthreads();

  if (wave == 0) {
    float zbv = zb[0];
    float4 zp = *(const float4*)zpart[lane];
    float z = zp.x + zp.y + zp.z + zp.w + zbv;
    float zs = spart[0] + spart[1] + spart[2] + spart[3] + zbv;
    float m = fmaxf(z, zs);
#pragma unroll
    for (int off = 1; off < 64; off <<= 1) m = fmaxf(m, __shfl_xor(m, off));
    float ez = __expf(z - m);
    float es = __expf(zs - m);
    float ssum = ez + (lane == 0 ? es : 0.f);
#pragma unroll
    for (int off = 1; off < 64; off <<= 1) ssum += __shfl_xor(ssum, off);
    float inv = 1.0f / ssum;
    ash[lane] = ez * inv;
    if (lane == 0) ash[64] = es * inv;
  }
  __syncthreads();

  size_t aoff = (size_t)bb * 2080 + (size_t)tt * 65;
  if (tid < 65) attn_out[aoff + tid] = ash[tid];

  const int e4 = tid & 127;          // float4 chunk
  const int ph = tid >> 7;           // p half (0: p<32, 1: p>=32)
  float4 cacc = {0.f, 0.f, 0.f, 0.f};
  const float* img = image + ((size_t)bb * 64 + (size_t)ph * 32) * 512 + e4 * 4;
  for (int p = 0; p < 32; ++p) {
    float a = ash[ph * 32 + p];
    float4 iv = *(const float4*)(img + (size_t)p * 512);
    cacc.x = __builtin_fmaf(a, iv.x, cacc.x);
    cacc.y = __builtin_fmaf(a, iv.y, cacc.y);
    cacc.z = __builtin_fmaf(a, iv.z, cacc.z);
    cacc.w = __builtin_fmaf(a, iv.w, cacc.w);
  }
  if (ph == 1) cpart[e4] = cacc;
  __syncthreads();
  if (ph == 0) {
    float4 o = cpart[e4];
    cacc.x += o.x; cacc.y += o.y; cacc.z += o.z; cacc.w += o.w;
    const bf16u* hsrow = hs_bf + (size_t)rown * 1024;
    int2 hraw = *(const int2*)(hsrow + e4 * 4);          // hh raw (4 bf16)
    int2 sraw = *(const int2*)(hsrow + 512 + e4 * 4);    // s raw (4 bf16)
    float a64 = ash[64];
    cacc.x += a64 * b2f((bf16u)(sraw.x & 0xffff)) + b2f((bf16u)(hraw.x & 0xffff));
    cacc.y += a64 * b2f((bf16u)((unsigned)sraw.x >> 16)) + b2f((bf16u)((unsigned)hraw.x >> 16));
    cacc.z += a64 * b2f((bf16u)(sraw.y & 0xffff)) + b2f((bf16u)(hraw.y & 0xffff));
    cacc.w += a64 * b2f((bf16u)((unsigned)sraw.y >> 16)) + b2f((bf16u)((unsigned)hraw.y >> 16));
    unsigned o0 = (unsigned)f2b(cacc.x) | ((unsigned)f2b(cacc.y) << 16);
    unsigned o1 = (unsigned)f2b(cacc.z) | ((unsigned)f2b(cacc.w) << 16);
    *(int2*)(ctx + (size_t)rown * 512 + e4 * 4) = make_int2((int)o0, (int)o1);
  }
}

// ---------------------------------------------------------------------------
// combine per-64col partials -> lse & rowmax.  One wave per row.
// ---------------------------------------------------------------------------
__global__ __launch_bounds__(256)
void reduce_lse(const float* __restrict__ pmax, const float* __restrict__ psum,
                float* __restrict__ lse, float* __restrict__ rmax)
{
  int row = blockIdx.x * 4 + (threadIdx.x >> 6);   // 4 waves/block, 512 blocks
  int lane = threadIdx.x & 63;
  const float* pm = pmax + (size_t)row * 470;
  const float* ps = psum + (size_t)row * 470;
  float m = -1e30f, s = 0.f;
  for (int c = lane; c < 470; c += 64) {
    float mi = pm[c];
    float si = ps[c];
    if (mi > m) { s = s * __expf(m - mi) + si; m = mi; }
    else        { s += si * __expf(mi - m); }
  }
#pragma unroll
  for (int off = 1; off < 64; off <<= 1) {
    float mo = __shfl_xor(m, off);
    float so = __shfl_xor(s, off);
    float mn = fmaxf(m, mo);
    s = s * __expf(m - mn) + so * __expf(mo - mn);
    m = mn;
  }
  if (lane == 0) {
    rmax[row] = m;
    lse[row] = m + logf(s);
  }
}

// ---------------------------------------------------------------------------
// logp = logit - lse (in place, float4).  out row rflat = b*32+t.
// ---------------------------------------------------------------------------
__global__ __launch_bounds__(256)
void finalize_kernel(float* __restrict__ out, const float* __restrict__ lse)
{
  int idx = blockIdx.x * 256 + threadIdx.x;   // 15,360,000 float4s
  if (idx >= 15360000) return;
  int rflat = idx / 7500;
  int c4 = idx - rflat * 7500;
  float L = lse[(rflat & 31) * 64 + (rflat >> 5)];
  float4* p = (float4*)(out + (size_t)rflat * 30000 + (size_t)c4 * 4);
  float4 v = *p;
  v.x -= L; v.y -= L; v.z -= L; v.w -= L;
  *p = v;
}

__global__ void slp_kernel(const float* __restrict__ rmax,
                           const float* __restrict__ lse, float* __restrict__ out)
{
  int b = threadIdx.x;              // 64 threads
  float s = 0.f;
  for (int t = 0; t < 32; ++t) { int r = t * 64 + b; s += rmax[r] - lse[r]; }
  out[61440000 + 133120 + b] = s;
}

// ---------------------------------------------------------------------------
extern "C" void kernel_launch(void* const* d_in, const int* in_sizes, int n_in,
                              void* d_out, int out_size, void* d_ws, size_t ws_size,
                              hipStream_t stream)
{
  const float* image   = (const float*)d_in[0];
  const float* vp      = (const float*)d_in[1];
  const float* lab     = (const float*)d_in[2];
  const float* topic   = (const float*)d_in[3];
  const float* temp    = (const float*)d_in[4];
  const int*   text    = (const int*)d_in[5];
  const float* wemb    = (const float*)d_in[6];
  const float* fc_v_w  = (const float*)d_in[7];
  const float* fc_v_b  = (const float*)d_in[8];
  const float* fc_h_w  = (const float*)d_in[9];
  const float* fc_h_b  = (const float*)d_in[10];
  const float* fc_m_w  = (const float*)d_in[11];
  const float* fc_m_b  = (const float*)d_in[12];
  const float* w_ih    = (const float*)d_in[13];
  const float* w_hh    = (const float*)d_in[14];
  const float* b_ih    = (const float*)d_in[15];
  const float* b_hh    = (const float*)d_in[16];
  const float* fc_w    = (const float*)d_in[17];
  const float* fc_b    = (const float*)d_in[18];
  const float* fc_hh_w = (const float*)d_in[19];
  const float* fc_hh_b = (const float*)d_in[20];
  const float* fc_s_w  = (const float*)d_in[21];
  const float* fc_s_b  = (const float*)d_in[22];
  const float* fc_z_w  = (const float*)d_in[23];
  const float* fc_z_b  = (const float*)d_in[24];
  const float* fc_p_w  = (const float*)d_in[25];
  const float* fc_p_b  = (const float*)d_in[26];
  float* out = (float*)d_out;

  char* base = (char*)d_ws;
  size_t off = 0;
  auto alloc = [&](size_t bytes) -> char* {
    char* p = base + off;
    off += (bytes + 255) & ~(size_t)255;
    return p;
  };
  bf16u* X       = (bf16u*)alloc(2048ull * 1568 * 2);   // dead after gates gemm
  bf16u* w_ih_bf = (bf16u*)alloc(2048ull * 1568 * 2);   // dead after gates gemm
  bf16u* gx_bf   = (bf16u*)alloc(2048ull * 2048 * 2);   // dead after lstm
  bf16u* image_bf= (bf16u*)alloc(4096ull * 512 * 2);    // dead after v gemm
  bf16u* wpackb  = (bf16u*)alloc(2048ull * 512 * 2);
  bf16u* fcv_bf  = (bf16u*)alloc(512ull * 512 * 2);
  bf16u* fcw_bf  = (bf16u*)alloc(1024ull * 512 * 2);
  bf16u* fchh_bf = (bf16u*)alloc(512ull * 512 * 2);
  bf16u* fcs_bf  = (bf16u*)alloc(512ull * 512 * 2);
  bf16u* fcp_bf  = (bf16u*)alloc(30000ull * 512 * 2);
  float* imean   = (float*)alloc(64ull * 512 * 4);
  float* h0b     = (float*)alloc(64ull * 512 * 4);
  float* m0b     = (float*)alloc(64ull * 512 * 4);
  bf16u* vbuf    = (bf16u*)alloc(4096ull * 512 * 2);
  bf16u* hA      = (bf16u*)alloc(64ull * 512 * 2);
  bf16u* hB      = (bf16u*)alloc(64ull * 512 * 2);
  unsigned* barb = (unsigned*)alloc(256);
  bf16u* h_all   = (bf16u*)alloc(2048ull * 512 * 2);
  float* rmaxb   = (float*)alloc(2048ull * 4);
  float* lseb    = (float*)alloc(2048ull * 4);
  // overlays (regions dead by the time these are written):
  bf16u* hs_bf   = (bf16u*)w_ih_bf;                     // 2048x1024 bf16 (4.2MB <= 6.4MB)
  bf16u* ctx     = (bf16u*)(w_ih_bf + 2048ull * 1024);  // 2048x512 bf16 (fits)
  bf16u* hhbuf   = (bf16u*)X;                           // 2048x512 bf16
  bf16u* sbuf    = (bf16u*)(X + 2048ull * 512);         // 2048x512 bf16 (fits in X)
  float* pmaxb   = (float*)gx_bf;                       // 2048x470 f32
  float* psumb   = (float*)(gx_bf + 2048ull * 2048);    // second half of gx region
  (void)in_sizes; (void)n_in; (void)out_size; (void)ws_size;

  // --- prep & conversions ---
  mean_kernel<<<64, 256, 0, stream>>>(image, imean);
  prep_kernel<<<64, 256, 0, stream>>>(imean, vp, lab, topic, text, wemb, X);
  cvt_kernel<<<12544, 256, 0, stream>>>(w_ih, w_ih_bf, 2048 * 1568);
  cvt_kernel<<<8192, 256, 0, stream>>>(image, image_bf, 4096 * 512);
  cvt_kernel<<<1024, 256, 0, stream>>>(fc_v_w, fcv_bf, 512 * 512);
  cvt_kernel<<<2048, 256, 0, stream>>>(fc_w, fcw_bf, 1024 * 512);
  cvt_kernel<<<1024, 256, 0, stream>>>(fc_hh_w, fchh_bf, 512 * 512);
  cvt_kernel<<<1024, 256, 0, stream>>>(fc_s_w, fcs_bf, 512 * 512);
  cvt_kernel<<<60000, 256, 0, stream>>>(fc_p_w, fcp_bf, 30000 * 512);
  pack_whh<<<4096, 256, 0, stream>>>(w_hh, wpackb);

  // gates_x = X @ w_ih^T + b_ih + b_hh  (2048x2048x1568) -> bf16
  gemm_bt<2><<<dim3(16, 16), 256, 0, stream>>>(X, 1568, w_ih_bf, 1568, b_ih, b_hh,
      gx_bf, 2048, 2048, 2048, 1568, 0, nullptr, nullptr, nullptr, nullptr);
  // v = image @ fc_v_w^T + b  (4096x512x512) -> bf16
  gemm_bt<2><<<dim3(4, 32), 256, 0, stream>>>(image_bf, 512, fcv_bf, 512, fc_v_b, nullptr,
      vbuf, 512, 4096, 512, 512, 0, nullptr, nullptr, nullptr, nullptr);
  // h0 / m0 scalar f32 (tiny)
  gemm_tmpl<32><<<dim3(2, 2), 256, 512 * 36 * 4, stream>>>(
      imean, 512, fc_h_w, 512, fc_h_b, h0b, 512, 64, 512, 512, 2);
  gemm_tmpl<32><<<dim3(2, 2), 256, 512 * 36 * 4, stream>>>(
      imean, 512, fc_m_w, 512, fc_m_b, m0b, 512, 64, 512, 512, 2);

  // --- LSTM: persistent 32-block kernel, all 32 timesteps ---
  init_state<<<128, 256, 0, stream>>>(h0b, hA, barb);
  const int lstm_lds = 65536 + 65536 + 64 * 65 * 4;   // 147,712 B
  lstm_all<<<32, 256, lstm_lds, stream>>>(wpackb, gx_bf, hA, hB, m0b, h_all, barb);

  // hs = relu(h_all @ fc_w^T + b)  (2048x1024x512) -> bf16
  gemm_bt<2><<<dim3(8, 16), 256, 0, stream>>>(h_all, 512, fcw_bf, 512, fc_b, nullptr,
      hs_bf, 1024, 2048, 1024, 512, 1, nullptr, nullptr, nullptr, nullptr);
  // _hh / _s  (2048x512x512) -> bf16
  gemm_bt<2><<<dim3(4, 16), 256, 0, stream>>>(hs_bf, 1024, fchh_bf, 512, fc_hh_b, nullptr,
      hhbuf, 512, 2048, 512, 512, 0, nullptr, nullptr, nullptr, nullptr);
  gemm_bt<2><<<dim3(4, 16), 256, 0, stream>>>(hs_bf + 512, 1024, fcs_bf, 512, fc_s_b, nullptr,
      sbuf, 512, 2048, 512, 512, 0, nullptr, nullptr, nullptr, nullptr);

  attn_kernel<<<2048, 256, 0, stream>>>(vbuf, image, hs_bf, hhbuf, sbuf,
      fc_z_w, fc_z_b, out + 61440000, ctx);

  // vocab projection + fused softmax stats (2048x30000x512), XCD-swizzled 1-D
  gemm_bt<1><<<dim3(3760), 256, 0, stream>>>(ctx, 512, fcp_bf, 512, fc_p_b, nullptr,
      nullptr, 0, 2048, 30000, 512, 0, temp, out, pmaxb, psumb);

  reduce_lse<<<512, 256, 0, stream>>>(pmaxb, psumb, lseb, rmaxb);
  finalize_kernel<<<60000, 256, 0, stream>>>(out, lseb);
  slp_kernel<<<1, 64, 0, stream>>>(rmaxb, lseb, out);
}

// Round 5
// 1174.886 us; speedup vs baseline: 1.1020x; 1.1020x over previous
//
#include <hip/hip_runtime.h>

// ---------------------------------------------------------------------------
// SentenceDecoder on MI355X — f32 I/O, bf16 MFMA internals.
// Dims: B=64, T=32, P=64, E=H=512, V=30000, IN=1568, rows = T*B = 2048.
// Output (flat f32): logp [64][32][30000] | attn [64][32][65] | slp [64]
// ---------------------------------------------------------------------------

typedef unsigned short bf16u;
typedef __attribute__((ext_vector_type(8))) short short8;   // MFMA A/B frag
typedef __attribute__((ext_vector_type(4))) float floatx4;  // MFMA C/D frag

#define DEV __device__ __forceinline__

DEV float b2f(bf16u u) { return __uint_as_float(((unsigned)u) << 16); }
DEV bf16u f2b(float f) {
  unsigned u = __float_as_uint(f);
  u = (u + 0x7fffu + ((u >> 16) & 1u)) >> 16;   // RNE
  return (bf16u)u;
}

// fast tanh: 1 - 2/(1+exp(2x)).  exp->inf => 1; exp->0 => -1.  ~5 instrs.
DEV float ftanh(float x) {
  float e = __expf(2.0f * x);
  float r = __builtin_amdgcn_rcpf(e + 1.0f);
  return __builtin_fmaf(-2.0f, r, 1.0f);
}
DEV float fsigm(float x) {
  return __builtin_amdgcn_rcpf(1.0f + __expf(-x));
}

// ---------------------------------------------------------------------------
// f32 -> bf16 conversion
// ---------------------------------------------------------------------------
__global__ __launch_bounds__(256)
void cvt_kernel(const float* __restrict__ src, bf16u* __restrict__ dst, int n)
{
  int i = blockIdx.x * 256 + threadIdx.x;
  if (i < n) dst[i] = f2b(src[i]);
}

// fused conversion of 4 small weight matrices (one launch instead of 4)
__global__ __launch_bounds__(256)
void cvt4_kernel(const float* __restrict__ s0, bf16u* __restrict__ d0, int n0,
                 const float* __restrict__ s1, bf16u* __restrict__ d1, int n1,
                 const float* __restrict__ s2, bf16u* __restrict__ d2, int n2,
                 const float* __restrict__ s3, bf16u* __restrict__ d3, int n3)
{
  int i = blockIdx.x * 256 + threadIdx.x;
  if (i < n0) d0[i] = f2b(s0[i]);
  if (i < n1) d1[i] = f2b(s1[i]);
  if (i < n2) d2[i] = f2b(s2[i]);
  if (i < n3) d3[i] = f2b(s3[i]);
}

// ---------------------------------------------------------------------------
// image mean over P=64 (f32)
// ---------------------------------------------------------------------------
__global__ __launch_bounds__(256)
void mean_kernel(const float* __restrict__ image, float* __restrict__ imean)
{
  int b = blockIdx.x;
  for (int e = threadIdx.x; e < 512; e += 256) {
    float s = 0.f;
    for (int p = 0; p < 64; ++p) s += image[(size_t)(b * 64 + p) * 512 + e];
    imean[b * 512 + e] = s * (1.0f / 64.0f);
  }
}

// ---------------------------------------------------------------------------
// X[t*64+b] (bf16) = [imean | vp | label | topic | emb[tok]]  width 1568
// ---------------------------------------------------------------------------
__global__ __launch_bounds__(256)
void prep_kernel(const float* __restrict__ imean, const float* __restrict__ vp,
                 const float* __restrict__ lab, const float* __restrict__ topic,
                 const int* __restrict__ text, const float* __restrict__ wemb,
                 bf16u* __restrict__ X)
{
  int b = blockIdx.x;
  for (int t = 0; t < 32; ++t) {
    bf16u* xr = X + ((size_t)t * 64 + b) * 1568;
    int tok = (t == 0) ? 0 : text[b * 32 + t - 1];
    for (int e = threadIdx.x; e < 512; e += 256) {
      xr[e] = f2b(imean[b * 512 + e]);
      xr[544 + e] = f2b(topic[b * 512 + e]);
      xr[1056 + e] = f2b(wemb[(size_t)tok * 512 + e]);
    }
    if (threadIdx.x < 16) {
      xr[512 + threadIdx.x] = f2b(vp[b * 16 + threadIdx.x]);
      xr[528 + threadIdx.x] = f2b(lab[b * 16 + threadIdx.x]);
    }
  }
}

// ---------------------------------------------------------------------------
// pack w_hh [2048][512] f32 -> bf16 wpack[blk][kg][rr][8]
// blk = (row&511)>>4, lc = row&15, gate = row>>9, rr = gate*16+lc, kg = k>>3
// ---------------------------------------------------------------------------
__global__ __launch_bounds__(256)
void pack_whh(const float* __restrict__ whh, bf16u* __restrict__ wpack)
{
  int idx = blockIdx.x * 256 + threadIdx.x;   // 2048*512
  int gr = idx >> 9, k = idx & 511;
  int gate = gr >> 9, win = gr & 511;
  int blk = win >> 4, lc = win & 15;
  int rr = gate * 16 + lc;
  wpack[(size_t)blk * 32768 + (((k >> 3) * 64 + rr) << 3) + (k & 7)] =
      f2b(whh[(size_t)gr * 512 + k]);
}

// ---------------------------------------------------------------------------
// MFMA GEMM (m97 pattern): C[m,n] = act( A[m,:].W[n,:] + bias1 (+bias2) )
// A: M x K bf16 (lda), W: N x K bf16 (ldw).  128x128 tile, BK=32, 2x2 waves.
// MODE 1: vocab epilogue, 1-D grid of 3760 blocks with XCD-chunked swizzle:
//         xcd = blk&7 owns runs of 16 slots -> one n-tile's 16 m-tiles stay
//         on one XCD (W panel fetched once per XCD L2, reused 16x).
// MODE 2: bf16 store to C, legacy 2-D grid (x = n-tile, y = m-tile).
// ---------------------------------------------------------------------------
#define BK 32
#define LDT 40

template<int MODE>
__global__ __launch_bounds__(256)
void gemm_bt(const bf16u* __restrict__ A, int lda,
             const bf16u* __restrict__ W, int ldw,
             const float* __restrict__ bias1, const float* __restrict__ bias2,
             bf16u* __restrict__ C, int ldc,
             int M, int N, int K, int act,
             const float* __restrict__ temp,
             float* __restrict__ outbase,
             float* __restrict__ pmax, float* __restrict__ psum)
{
  __shared__ __align__(16) bf16u As[128 * LDT];
  __shared__ __align__(16) bf16u Ws[128 * LDT];
  const int tid = threadIdx.x;
  int m0, n0, ntile = 0;
  if (MODE == 1) {
    // 3760 blocks; xcd p&7, slot p>>3 (0..469).  16 consecutive slots on one
    // xcd -> one n-tile.  slots<464: nt=(slot>>4)*8+xcd covers nt 0..231;
    // tail 6 slots x 8 xcds = 48 blocks cover nt 232..234.
    int p = blockIdx.x;
    int xcd = p & 7, slot = p >> 3;
    int nt, mt;
    if (slot < 464) { nt = (slot >> 4) * 8 + xcd; mt = slot & 15; }
    else { int idx = (slot - 464) * 8 + xcd; nt = 232 + (idx >> 4); mt = idx & 15; }
    m0 = mt * 128; n0 = nt * 128; ntile = nt;
  } else {
    n0 = blockIdx.x * 128;
    m0 = blockIdx.y * 128;
  }
  const int wave = tid >> 6, lane = tid & 63;
  const int wm = wave >> 1, wn = wave & 1;
  const int q = lane >> 4, l16 = lane & 15;
  const int r0 = tid >> 2, s0 = tid & 3;

  const floatx4 zero = {0.f, 0.f, 0.f, 0.f};
  floatx4 acc[4][4];
#pragma unroll
  for (int i = 0; i < 4; ++i)
#pragma unroll
    for (int j = 0; j < 4; ++j) acc[i][j] = zero;

  int ar0 = m0 + r0;      if (ar0 >= M) ar0 = M - 1;
  int ar1 = m0 + r0 + 64; if (ar1 >= M) ar1 = M - 1;
  int wr0 = n0 + r0;      if (wr0 >= N) wr0 = N - 1;
  int wr1 = n0 + r0 + 64; if (wr1 >= N) wr1 = N - 1;
  const bf16u* Ap0 = A + (size_t)ar0 * lda + s0 * 8;
  const bf16u* Ap1 = A + (size_t)ar1 * lda + s0 * 8;
  const bf16u* Wp0 = W + (size_t)wr0 * ldw + s0 * 8;
  const bf16u* Wp1 = W + (size_t)wr1 * ldw + s0 * 8;

  for (int k0 = 0; k0 < K; k0 += BK) {
    const int4 a0 = *(const int4*)(Ap0 + k0);
    const int4 a1 = *(const int4*)(Ap1 + k0);
    const int4 w0 = *(const int4*)(Wp0 + k0);
    const int4 w1 = *(const int4*)(Wp1 + k0);
    __syncthreads();
    *(int4*)(As + r0 * LDT + s0 * 8) = a0;
    *(int4*)(As + (r0 + 64) * LDT + s0 * 8) = a1;
    *(int4*)(Ws + r0 * LDT + s0 * 8) = w0;
    *(int4*)(Ws + (r0 + 64) * LDT + s0 * 8) = w1;
    __syncthreads();
    short8 af[4], wf[4];
#pragma unroll
    for (int i = 0; i < 4; ++i) {
      af[i] = *(const short8*)(As + (wm * 64 + i * 16 + l16) * LDT + q * 8);
      wf[i] = *(const short8*)(Ws + (wn * 64 + i * 16 + l16) * LDT + q * 8);
    }
#pragma unroll
    for (int i = 0; i < 4; ++i)
#pragma unroll
      for (int j = 0; j < 4; ++j)
        acc[i][j] = __builtin_amdgcn_mfma_f32_16x16x32_bf16(af[i], wf[j], acc[i][j], 0, 0, 0);
  }

  // C/D layout: col = lane&15, row = (lane>>4)*4 + reg
  int colb[4]; float bias[4];
#pragma unroll
  for (int j = 0; j < 4; ++j) {
    int col = n0 + wn * 64 + j * 16 + l16;
    colb[j] = col;
    int cc = col < N ? col : N - 1;
    float bv = 0.f;
    if (bias1) bv += bias1[cc];
    if (bias2) bv += bias2[cc];
    bias[j] = bv;
  }

  if (MODE == 2) {
#pragma unroll
    for (int i = 0; i < 4; ++i) {
#pragma unroll
      for (int r = 0; r < 4; ++r) {
        int row = m0 + wm * 64 + i * 16 + q * 4 + r;
        if (row < M) {
#pragma unroll
          for (int j = 0; j < 4; ++j) {
            int col = colb[j];
            if (col < N) {
              float v = acc[i][j][r] + bias[j];
              if (act == 1) v = fmaxf(v, 0.f);
              C[(size_t)row * ldc + col] = f2b(v);
            }
          }
        }
      }
    }
  } else {   // MODE 1: vocab
    int pc = ntile * 2 + wn;   // 64-col slice (< 470)
#pragma unroll
    for (int i = 0; i < 4; ++i) {
#pragma unroll
      for (int r = 0; r < 4; ++r) {
        int row = m0 + wm * 64 + i * 16 + q * 4 + r;   // t*64 + b
        int bb = row & 63, tt = row >> 6;
        float rt = 1.0f / temp[bb];
        float vals[4];
#pragma unroll
        for (int j = 0; j < 4; ++j) {
          int col = colb[j];
          float v = (acc[i][j][r] + bias[j]) * rt;
          if (col < N) {
            outbase[(size_t)bb * 960000 + (size_t)tt * 30000 + col] = v;
            vals[j] = v;
          } else vals[j] = -1e30f;
        }
        float mx = fmaxf(fmaxf(vals[0], vals[1]), fmaxf(vals[2], vals[3]));
#pragma unroll
        for (int off = 1; off < 16; off <<= 1) mx = fmaxf(mx, __shfl_xor(mx, off));
        float s = 0.f;
#pragma unroll
        for (int j = 0; j < 4; ++j)
          s += (vals[j] > -1e29f) ? __expf(vals[j] - mx) : 0.f;
#pragma unroll
        for (int off = 1; off < 16; off <<= 1) s += __shfl_xor(s, off);
        if (l16 == 0) {
          pmax[(size_t)row * 470 + pc] = mx;
          psum[(size_t)row * 470 + pc] = s;
        }
      }
    }
  }
}

// ---------------------------------------------------------------------------
// scalar f32 GEMM for tiny h0/m0 (M=64)
// ---------------------------------------------------------------------------
template<int ROWS>
__global__ void gemm_tmpl(const float* __restrict__ A, int lda,
                          const float* __restrict__ W, int ldw,
                          const float* __restrict__ bias1,
                          float* __restrict__ C, int ldc,
                          int M, int N, int K, int act)
{
  constexpr int RP = ROWS + 4;
  extern __shared__ __align__(16) float Ash[];
  const int tid = threadIdx.x;
  const int m0 = blockIdx.y * ROWS;
  const int n0 = blockIdx.x * 256;
  for (int idx = tid; idx < ROWS * K; idx += 256) {
    int r = idx / K, k = idx - r * K;
    int rr = m0 + r; if (rr >= M) rr = M - 1;
    Ash[k * RP + r] = A[(size_t)rr * lda + k];
  }
  __syncthreads();
  int n = n0 + tid;
  if (n >= N) return;
  float acc[ROWS];
#pragma unroll
  for (int r = 0; r < ROWS; ++r) acc[r] = 0.f;
  const float* wr = W + (size_t)n * ldw;
  for (int k = 0; k < K; ++k) {
    float w = wr[k];
    const float* a = Ash + (size_t)k * RP;
#pragma unroll
    for (int r = 0; r < ROWS; ++r) acc[r] += w * a[r];
  }
  float bv = bias1 ? bias1[n] : 0.f;
#pragma unroll
  for (int r = 0; r < ROWS; ++r) {
    int row = m0 + r;
    if (row < M) {
      float v = acc[r] + bv;
      if (act == 1) v = fmaxf(v, 0.f);
      else if (act == 2) v = tanhf(v);
      C[(size_t)row * ldc + n] = v;
    }
  }
}

// ---------------------------------------------------------------------------
// init LSTM state: pack h0 (f32) into packed bf16 layout, copy m0 f32
// packed pos for h[b][jj]: ((jj>>3)*64 + b)*8 + (jj&7)
// ---------------------------------------------------------------------------
__global__ __launch_bounds__(256)
void init_state(const float* __restrict__ h0b, const float* __restrict__ m0b,
                bf16u* __restrict__ hOut, float* __restrict__ mbuf)
{
  int i = blockIdx.x * 256 + threadIdx.x;   // 32768
  int b = i >> 9, jj = i & 511;
  hOut[(((jj >> 3) * 64 + b) << 3) + (jj & 7)] = f2b(h0b[i]);
  mbuf[i] = m0b[i];
}

// ---------------------------------------------------------------------------
// LSTM timestep (launched 32x): 32 blocks, block owns 16 h-cols (64 gate rows).
// LDS: h packed (64KB) + weight slice packed (64KB) + gates f32 (16.6KB).
// gates[b][rr] = h@wslice^T via MFMA; pointwise -> hOut (packed), h_all, mbuf.
// (Persistent single-launch variant tried in R4: per-step device-scope
//  fence+barrier cost ~6us/step > 3us launch overhead.  Chain is faster.)
// ---------------------------------------------------------------------------
__global__ __launch_bounds__(256)
void lstm_step(const bf16u* __restrict__ wpack, const bf16u* __restrict__ gx,
               const bf16u* __restrict__ hIn, bf16u* __restrict__ hOut,
               float* __restrict__ mbuf, bf16u* __restrict__ h_all, int t)
{
  extern __shared__ __align__(16) char smem[];
  bf16u* hsh = (bf16u*)smem;                 // 32768 bf16, [kg][b][8]
  bf16u* wsh = (bf16u*)(smem + 65536);       // 32768 bf16, [kg][rr][8]
  float* gsh = (float*)(smem + 131072);      // [64][65]
  const int blk = blockIdx.x, tid = threadIdx.x;

  const int4* hsrc = (const int4*)hIn;
  const int4* wsrc = (const int4*)(wpack + (size_t)blk * 32768);
  int4* hdst = (int4*)hsh; int4* wdst = (int4*)wsh;
#pragma unroll
  for (int u = 0; u < 16; ++u) {             // 4096 int4 each
    hdst[tid + 256 * u] = hsrc[tid + 256 * u];
    wdst[tid + 256 * u] = wsrc[tid + 256 * u];
  }
  __syncthreads();

  const int wave = tid >> 6, lane = tid & 63;
  const int wm = wave >> 1, wn = wave & 1, q = lane >> 4, l16 = lane & 15;
  const floatx4 zero = {0.f, 0.f, 0.f, 0.f};
  floatx4 acc[2][2];
#pragma unroll
  for (int i = 0; i < 2; ++i)
#pragma unroll
    for (int j = 0; j < 2; ++j) acc[i][j] = zero;

  for (int s = 0; s < 16; ++s) {
    short8 af[2], wf[2];
#pragma unroll
    for (int i = 0; i < 2; ++i)
      af[i] = *(const short8*)(hsh + ((((s * 4 + q) * 64) + wm * 32 + i * 16 + l16) << 3));
#pragma unroll
    for (int j = 0; j < 2; ++j)
      wf[j] = *(const short8*)(wsh + ((((s * 4 + q) * 64) + wn * 32 + j * 16 + l16) << 3));
#pragma unroll
    for (int i = 0; i < 2; ++i)
#pragma unroll
      for (int j = 0; j < 2; ++j)
        acc[i][j] = __builtin_amdgcn_mfma_f32_16x16x32_bf16(af[i], wf[j], acc[i][j], 0, 0, 0);
  }
  // D: col(rr) = lane&15 (+tile), row(b) = q*4+reg (+tile)
#pragma unroll
  for (int i = 0; i < 2; ++i)
#pragma unroll
    for (int j = 0; j < 2; ++j)
#pragma unroll
      for (int r = 0; r < 4; ++r)
        gsh[(wn * 32 + j * 16 + l16) * 65 + (wm * 32 + i * 16 + q * 4 + r)] = acc[i][j][r];
  __syncthreads();

#pragma unroll
  for (int u = 0; u < 4; ++u) {
    int p = tid + 256 * u;            // 1024 pairs
    int b = p >> 4, lc = p & 15;
    int jj = blk * 16 + lc;
    const bf16u* gxr = gx + ((size_t)t * 64 + b) * 2048;
    float ai = gsh[(lc) * 65 + b]        + b2f(gxr[jj]);
    float af = gsh[(16 + lc) * 65 + b]   + b2f(gxr[512 + jj]);
    float ag = gsh[(32 + lc) * 65 + b]   + b2f(gxr[1024 + jj]);
    float ao = gsh[(48 + lc) * 65 + b]   + b2f(gxr[1536 + jj]);
    float iv = fsigm(ai);
    float fv = fsigm(af);
    float gv = ftanh(ag);
    float ov = fsigm(ao);
    float mm = fv * mbuf[b * 512 + jj] + iv * gv;
    float hn = ov * ftanh(mm);
    mbuf[b * 512 + jj] = mm;
    bf16u hb = f2b(hn);
    hOut[(((jj >> 3) * 64 + b) << 3) + (jj & 7)] = hb;
    h_all[((size_t)t * 64 + b) * 512 + jj] = hb;
  }
}

// ---------------------------------------------------------------------------
// attention per (t,b) row — wave w owns k-quarter, lane l owns p = l.
// ---------------------------------------------------------------------------
__global__ __launch_bounds__(256)
void attn_kernel(const bf16u* __restrict__ vbuf, const float* __restrict__ image,
                 const bf16u* __restrict__ hs_bf, const bf16u* __restrict__ hh2,
                 const bf16u* __restrict__ s2, const float* __restrict__ wz,
                 const float* __restrict__ zb, float* __restrict__ attn_out,
                 bf16u* __restrict__ ctx)
{
  const int rown = blockIdx.x;            // t*64 + b
  const int bb = rown & 63, tt = rown >> 6;
  const int tid = threadIdx.x;
  const int wave = tid >> 6, lane = tid & 63;

  __shared__ float2 hwz[512];        // (hh, wz) per k
  __shared__ float zpart[64][4];     // per-p per-wave z partials
  __shared__ float spart[4];         // s-row per-wave partials
  __shared__ float ash[66];
  __shared__ float4 cpart[128];

  float sv0, sv1;
  {
    unsigned hr = *(const unsigned*)(hh2 + (size_t)rown * 512 + tid * 2);
    unsigned sr = *(const unsigned*)(s2 + (size_t)rown * 512 + tid * 2);
    float2 w2 = *(const float2*)(wz + tid * 2);
    hwz[tid * 2]     = make_float2(b2f((bf16u)(hr & 0xffffu)), w2.x);
    hwz[tid * 2 + 1] = make_float2(b2f((bf16u)(hr >> 16)), w2.y);
    sv0 = b2f((bf16u)(sr & 0xffffu));
    sv1 = b2f((bf16u)(sr >> 16));
  }
  __syncthreads();

  {
    const bf16u* vrow = vbuf + (size_t)(bb * 64 + lane) * 512 + wave * 128;
    float acc = 0.f;
    for (int c = 0; c < 16; ++c) {
      short8 vv = *(const short8*)(vrow + c * 8);
#pragma unroll
      for (int e = 0; e < 8; ++e) {
        float2 hz = hwz[wave * 128 + c * 8 + e];   // wave-uniform -> broadcast
        float tn = ftanh(b2f((bf16u)vv[e]) + hz.x);
        acc = __builtin_fmaf(tn, hz.y, acc);
      }
    }
    zpart[lane][wave] = acc;
  }

  {
    float2 h0 = hwz[tid * 2], h1 = hwz[tid * 2 + 1];
    float sacc = ftanh(sv0 + h0.x) * h0.y + ftanh(sv1 + h1.x) * h1.y;
#pragma unroll
    for (int off = 1; off < 64; off <<= 1) sacc += __shfl_xor(sacc, off);
    if (lane == 0) spart[wave] = sacc;
  }
  __syncthreads();

  if (wave == 0) {
    float zbv = zb[0];
    float4 zp = *(const float4*)zpart[lane];
    float z = zp.x + zp.y + zp.z + zp.w + zbv;
    float zs = spart[0] + spart[1] + spart[2] + spart[3] + zbv;
    float m = fmaxf(z, zs);
#pragma unroll
    for (int off = 1; off < 64; off <<= 1) m = fmaxf(m, __shfl_xor(m, off));
    float ez = __expf(z - m);
    float es = __expf(zs - m);
    float ssum = ez + (lane == 0 ? es : 0.f);
#pragma unroll
    for (int off = 1; off < 64; off <<= 1) ssum += __shfl_xor(ssum, off);
    float inv = 1.0f / ssum;
    ash[lane] = ez * inv;
    if (lane == 0) ash[64] = es * inv;
  }
  __syncthreads();

  size_t aoff = (size_t)bb * 2080 + (size_t)tt * 65;
  if (tid < 65) attn_out[aoff + tid] = ash[tid];

  const int e4 = tid & 127;          // float4 chunk
  const int ph = tid >> 7;           // p half (0: p<32, 1: p>=32)
  float4 cacc = {0.f, 0.f, 0.f, 0.f};
  const float* img = image + ((size_t)bb * 64 + (size_t)ph * 32) * 512 + e4 * 4;
  for (int p = 0; p < 32; ++p) {
    float a = ash[ph * 32 + p];
    float4 iv = *(const float4*)(img + (size_t)p * 512);
    cacc.x = __builtin_fmaf(a, iv.x, cacc.x);
    cacc.y = __builtin_fmaf(a, iv.y, cacc.y);
    cacc.z = __builtin_fmaf(a, iv.z, cacc.z);
    cacc.w = __builtin_fmaf(a, iv.w, cacc.w);
  }
  if (ph == 1) cpart[e4] = cacc;
  __syncthreads();
  if (ph == 0) {
    float4 o = cpart[e4];
    cacc.x += o.x; cacc.y += o.y; cacc.z += o.z; cacc.w += o.w;
    const bf16u* hsrow = hs_bf + (size_t)rown * 1024;
    int2 hraw = *(const int2*)(hsrow + e4 * 4);          // hh raw (4 bf16)
    int2 sraw = *(const int2*)(hsrow + 512 + e4 * 4);    // s raw (4 bf16)
    float a64 = ash[64];
    cacc.x += a64 * b2f((bf16u)(sraw.x & 0xffff)) + b2f((bf16u)(hraw.x & 0xffff));
    cacc.y += a64 * b2f((bf16u)((unsigned)sraw.x >> 16)) + b2f((bf16u)((unsigned)hraw.x >> 16));
    cacc.z += a64 * b2f((bf16u)(sraw.y & 0xffff)) + b2f((bf16u)(hraw.y & 0xffff));
    cacc.w += a64 * b2f((bf16u)((unsigned)sraw.y >> 16)) + b2f((bf16u)((unsigned)hraw.y >> 16));
    unsigned o0 = (unsigned)f2b(cacc.x) | ((unsigned)f2b(cacc.y) << 16);
    unsigned o1 = (unsigned)f2b(cacc.z) | ((unsigned)f2b(cacc.w) << 16);
    *(int2*)(ctx + (size_t)rown * 512 + e4 * 4) = make_int2((int)o0, (int)o1);
  }
}

// ---------------------------------------------------------------------------
// combine per-64col partials -> lse & rowmax.  One wave per row.
// ---------------------------------------------------------------------------
__global__ __launch_bounds__(256)
void reduce_lse(const float* __restrict__ pmax, const float* __restrict__ psum,
                float* __restrict__ lse, float* __restrict__ rmax)
{
  int row = blockIdx.x * 4 + (threadIdx.x >> 6);   // 4 waves/block, 512 blocks
  int lane = threadIdx.x & 63;
  const float* pm = pmax + (size_t)row * 470;
  const float* ps = psum + (size_t)row * 470;
  float m = -1e30f, s = 0.f;
  for (int c = lane; c < 470; c += 64) {
    float mi = pm[c];
    float si = ps[c];
    if (mi > m) { s = s * __expf(m - mi) + si; m = mi; }
    else        { s += si * __expf(mi - m); }
  }
#pragma unroll
  for (int off = 1; off < 64; off <<= 1) {
    float mo = __shfl_xor(m, off);
    float so = __shfl_xor(s, off);
    float mn = fmaxf(m, mo);
    s = s * __expf(m - mn) + so * __expf(mo - mn);
    m = mn;
  }
  if (lane == 0) {
    rmax[row] = m;
    lse[row] = m + logf(s);
  }
}

// ---------------------------------------------------------------------------
// logp = logit - lse (in place, float4).  out row rflat = b*32+t.
// ---------------------------------------------------------------------------
__global__ __launch_bounds__(256)
void finalize_kernel(float* __restrict__ out, const float* __restrict__ lse)
{
  int idx = blockIdx.x * 256 + threadIdx.x;   // 15,360,000 float4s
  if (idx >= 15360000) return;
  int rflat = idx / 7500;
  int c4 = idx - rflat * 7500;
  float L = lse[(rflat & 31) * 64 + (rflat >> 5)];
  float4* p = (float4*)(out + (size_t)rflat * 30000 + (size_t)c4 * 4);
  float4 v = *p;
  v.x -= L; v.y -= L; v.z -= L; v.w -= L;
  *p = v;
}

__global__ void slp_kernel(const float* __restrict__ rmax,
                           const float* __restrict__ lse, float* __restrict__ out)
{
  int b = threadIdx.x;              // 64 threads
  float s = 0.f;
  for (int t = 0; t < 32; ++t) { int r = t * 64 + b; s += rmax[r] - lse[r]; }
  out[61440000 + 133120 + b] = s;
}

// ---------------------------------------------------------------------------
extern "C" void kernel_launch(void* const* d_in, const int* in_sizes, int n_in,
                              void* d_out, int out_size, void* d_ws, size_t ws_size,
                              hipStream_t stream)
{
  const float* image   = (const float*)d_in[0];
  const float* vp      = (const float*)d_in[1];
  const float* lab     = (const float*)d_in[2];
  const float* topic   = (const float*)d_in[3];
  const float* temp    = (const float*)d_in[4];
  const int*   text    = (const int*)d_in[5];
  const float* wemb    = (const float*)d_in[6];
  const float* fc_v_w  = (const float*)d_in[7];
  const float* fc_v_b  = (const float*)d_in[8];
  const float* fc_h_w  = (const float*)d_in[9];
  const float* fc_h_b  = (const float*)d_in[10];
  const float* fc_m_w  = (const float*)d_in[11];
  const float* fc_m_b  = (const float*)d_in[12];
  const float* w_ih    = (const float*)d_in[13];
  const float* w_hh    = (const float*)d_in[14];
  const float* b_ih    = (const float*)d_in[15];
  const float* b_hh    = (const float*)d_in[16];
  const float* fc_w    = (const float*)d_in[17];
  const float* fc_b    = (const float*)d_in[18];
  const float* fc_hh_w = (const float*)d_in[19];
  const float* fc_hh_b = (const float*)d_in[20];
  const float* fc_s_w  = (const float*)d_in[21];
  const float* fc_s_b  = (const float*)d_in[22];
  const float* fc_z_w  = (const float*)d_in[23];
  const float* fc_z_b  = (const float*)d_in[24];
  const float* fc_p_w  = (const float*)d_in[25];
  const float* fc_p_b  = (const float*)d_in[26];
  float* out = (float*)d_out;

  char* base = (char*)d_ws;
  size_t off = 0;
  auto alloc = [&](size_t bytes) -> char* {
    char* p = base + off;
    off += (bytes + 255) & ~(size_t)255;
    return p;
  };
  bf16u* X       = (bf16u*)alloc(2048ull * 1568 * 2);   // dead after gates gemm
  bf16u* w_ih_bf = (bf16u*)alloc(2048ull * 1568 * 2);   // dead after gates gemm
  bf16u* gx_bf   = (bf16u*)alloc(2048ull * 2048 * 2);   // dead after lstm
  bf16u* image_bf= (bf16u*)alloc(4096ull * 512 * 2);    // dead after v gemm
  bf16u* wpackb  = (bf16u*)alloc(2048ull * 512 * 2);
  bf16u* fcv_bf  = (bf16u*)alloc(512ull * 512 * 2);
  bf16u* fcw_bf  = (bf16u*)alloc(1024ull * 512 * 2);
  bf16u* fchh_bf = (bf16u*)alloc(512ull * 512 * 2);
  bf16u* fcs_bf  = (bf16u*)alloc(512ull * 512 * 2);
  bf16u* fcp_bf  = (bf16u*)alloc(30000ull * 512 * 2);
  float* imean   = (float*)alloc(64ull * 512 * 4);
  float* h0b     = (float*)alloc(64ull * 512 * 4);
  float* m0b     = (float*)alloc(64ull * 512 * 4);
  bf16u* vbuf    = (bf16u*)alloc(4096ull * 512 * 2);
  bf16u* hA      = (bf16u*)alloc(64ull * 512 * 2);
  bf16u* hB      = (bf16u*)alloc(64ull * 512 * 2);
  float* mbuf    = (float*)alloc(64ull * 512 * 4);
  bf16u* h_all   = (bf16u*)alloc(2048ull * 512 * 2);
  float* rmaxb   = (float*)alloc(2048ull * 4);
  float* lseb    = (float*)alloc(2048ull * 4);
  // overlays (regions dead by the time these are written):
  bf16u* hs_bf   = (bf16u*)w_ih_bf;                     // 2048x1024 bf16 (4.2MB <= 6.4MB)
  bf16u* ctx     = (bf16u*)(w_ih_bf + 2048ull * 1024);  // 2048x512 bf16 (fits)
  bf16u* hhbuf   = (bf16u*)X;                           // 2048x512 bf16
  bf16u* sbuf    = (bf16u*)(X + 2048ull * 512);         // 2048x512 bf16 (fits in X)
  float* pmaxb   = (float*)gx_bf;                       // 2048x470 f32
  float* psumb   = (float*)(gx_bf + 2048ull * 2048);    // second half of gx region
  (void)in_sizes; (void)n_in; (void)out_size; (void)ws_size;

  // --- prep & conversions ---
  mean_kernel<<<64, 256, 0, stream>>>(image, imean);
  prep_kernel<<<64, 256, 0, stream>>>(imean, vp, lab, topic, text, wemb, X);
  cvt_kernel<<<12544, 256, 0, stream>>>(w_ih, w_ih_bf, 2048 * 1568);
  cvt_kernel<<<8192, 256, 0, stream>>>(image, image_bf, 4096 * 512);
  cvt4_kernel<<<2048, 256, 0, stream>>>(fc_w, fcw_bf, 1024 * 512,
                                        fc_v_w, fcv_bf, 512 * 512,
                                        fc_hh_w, fchh_bf, 512 * 512,
                                        fc_s_w, fcs_bf, 512 * 512);
  cvt_kernel<<<60000, 256, 0, stream>>>(fc_p_w, fcp_bf, 30000 * 512);
  pack_whh<<<4096, 256, 0, stream>>>(w_hh, wpackb);

  // gates_x = X @ w_ih^T + b_ih + b_hh  (2048x2048x1568) -> bf16
  gemm_bt<2><<<dim3(16, 16), 256, 0, stream>>>(X, 1568, w_ih_bf, 1568, b_ih, b_hh,
      gx_bf, 2048, 2048, 2048, 1568, 0, nullptr, nullptr, nullptr, nullptr);
  // v = image @ fc_v_w^T + b  (4096x512x512) -> bf16
  gemm_bt<2><<<dim3(4, 32), 256, 0, stream>>>(image_bf, 512, fcv_bf, 512, fc_v_b, nullptr,
      vbuf, 512, 4096, 512, 512, 0, nullptr, nullptr, nullptr, nullptr);
  // h0 / m0 scalar f32 (tiny)
  gemm_tmpl<32><<<dim3(2, 2), 256, 512 * 36 * 4, stream>>>(
      imean, 512, fc_h_w, 512, fc_h_b, h0b, 512, 64, 512, 512, 2);
  gemm_tmpl<32><<<dim3(2, 2), 256, 512 * 36 * 4, stream>>>(
      imean, 512, fc_m_w, 512, fc_m_b, m0b, 512, 64, 512, 512, 2);

  // --- LSTM: 32 per-timestep MFMA launches ---
  init_state<<<128, 256, 0, stream>>>(h0b, m0b, hA, mbuf);
  const int lstm_lds = 65536 + 65536 + 64 * 65 * 4;   // 147,712 B
  for (int t = 0; t < 32; ++t) {
    const bf16u* hi = (t & 1) ? hB : hA;
    bf16u* ho = (t & 1) ? hA : hB;
    lstm_step<<<32, 256, lstm_lds, stream>>>(wpackb, gx_bf, hi, ho, mbuf, h_all, t);
  }

  // hs = relu(h_all @ fc_w^T + b)  (2048x1024x512) -> bf16
  gemm_bt<2><<<dim3(8, 16), 256, 0, stream>>>(h_all, 512, fcw_bf, 512, fc_b, nullptr,
      hs_bf, 1024, 2048, 1024, 512, 1, nullptr, nullptr, nullptr, nullptr);
  // _hh / _s  (2048x512x512) -> bf16
  gemm_bt<2><<<dim3(4, 16), 256, 0, stream>>>(hs_bf, 1024, fchh_bf, 512, fc_hh_b, nullptr,
      hhbuf, 512, 2048, 512, 512, 0, nullptr, nullptr, nullptr, nullptr);
  gemm_bt<2><<<dim3(4, 16), 256, 0, stream>>>(hs_bf + 512, 1024, fcs_bf, 512, fc_s_b, nullptr,
      sbuf, 512, 2048, 512, 512, 0, nullptr, nullptr, nullptr, nullptr);

  attn_kernel<<<2048, 256, 0, stream>>>(vbuf, image, hs_bf, hhbuf, sbuf,
      fc_z_w, fc_z_b, out + 61440000, ctx);

  // vocab projection + fused softmax stats (2048x30000x512), XCD-swizzled 1-D
  gemm_bt<1><<<dim3(3760), 256, 0, stream>>>(ctx, 512, fcp_bf, 512, fc_p_b, nullptr,
      nullptr, 0, 2048, 30000, 512, 0, temp, out, pmaxb, psumb);

  reduce_lse<<<512, 256, 0, stream>>>(pmaxb, psumb, lseb, rmaxb);
  finalize_kernel<<<60000, 256, 0, stream>>>(out, lseb);
  slp_kernel<<<1, 64, 0, stream>>>(rmaxb, lseb, out);
}

// Round 7
// 1028.562 us; speedup vs baseline: 1.2587x; 1.1423x over previous
//
#include <hip/hip_runtime.h>

// ---------------------------------------------------------------------------
// SentenceDecoder on MI355X — f32 I/O, bf16 MFMA internals.
// Dims: B=64, T=32, P=64, E=H=512, V=30000, IN=1568, rows = T*B = 2048.
// Output (flat f32): logp [64][32][30000] | attn [64][32][65] | slp [64]
// ---------------------------------------------------------------------------

typedef unsigned short bf16u;
typedef __attribute__((ext_vector_type(8))) short short8;   // MFMA A/B frag
typedef __attribute__((ext_vector_type(4))) float floatx4;  // MFMA C/D frag

#define DEV __device__ __forceinline__

DEV float b2f(bf16u u) { return __uint_as_float(((unsigned)u) << 16); }
DEV bf16u f2b(float f) {
  unsigned u = __float_as_uint(f);
  u = (u + 0x7fffu + ((u >> 16) & 1u)) >> 16;   // RNE
  return (bf16u)u;
}

// fast tanh: 1 - 2/(1+exp(2x)).  exp->inf => 1; exp->0 => -1.  ~5 instrs.
DEV float ftanh(float x) {
  float e = __expf(2.0f * x);
  float r = __builtin_amdgcn_rcpf(e + 1.0f);
  return __builtin_fmaf(-2.0f, r, 1.0f);
}
DEV float fsigm(float x) {
  return __builtin_amdgcn_rcpf(1.0f + __expf(-x));
}

// ---------------------------------------------------------------------------
// fused image-mean + X prep (block b; imean of b only needed by b's rows)
// X[t*64+b] (bf16) = [imean | vp | label | topic | emb[tok]]  width 1568
// ---------------------------------------------------------------------------
__global__ __launch_bounds__(256)
void mean_prep(const float* __restrict__ image, const float* __restrict__ vp,
               const float* __restrict__ lab, const float* __restrict__ topic,
               const int* __restrict__ text, const float* __restrict__ wemb,
               float* __restrict__ imean, bf16u* __restrict__ X)
{
  int b = blockIdx.x;
  __shared__ float ims[512];
  for (int e = threadIdx.x; e < 512; e += 256) {
    float s = 0.f;
    for (int p = 0; p < 64; ++p) s += image[(size_t)(b * 64 + p) * 512 + e];
    float v = s * (1.0f / 64.0f);
    imean[b * 512 + e] = v;
    ims[e] = v;
  }
  __syncthreads();
  for (int t = 0; t < 32; ++t) {
    bf16u* xr = X + ((size_t)t * 64 + b) * 1568;
    int tok = (t == 0) ? 0 : text[b * 32 + t - 1];
    for (int e = threadIdx.x; e < 512; e += 256) {
      xr[e] = f2b(ims[e]);
      xr[544 + e] = f2b(topic[b * 512 + e]);
      xr[1056 + e] = f2b(wemb[(size_t)tok * 512 + e]);
    }
    if (threadIdx.x < 16) {
      xr[512 + threadIdx.x] = f2b(vp[b * 16 + threadIdx.x]);
      xr[528 + threadIdx.x] = f2b(lab[b * 16 + threadIdx.x]);
    }
  }
}

// ---------------------------------------------------------------------------
// all weight conversions + w_hh pack in ONE launch (region-dispatched).
// regions (elem offsets): w_ih 3211264 | image 2097152 | fc_w 524288 |
// fc_v 262144 | fc_hh 262144 | fc_s 262144 | fc_p 15360000 | whh-pack 1048576
// total 23,027,712 = 256 * 89,952 blocks
// ---------------------------------------------------------------------------
__global__ __launch_bounds__(256)
void mega_cvt(const float* __restrict__ w_ih, bf16u* __restrict__ w_ih_bf,
              const float* __restrict__ image, bf16u* __restrict__ image_bf,
              const float* __restrict__ fc_w, bf16u* __restrict__ fcw_bf,
              const float* __restrict__ fc_v_w, bf16u* __restrict__ fcv_bf,
              const float* __restrict__ fc_hh_w, bf16u* __restrict__ fchh_bf,
              const float* __restrict__ fc_s_w, bf16u* __restrict__ fcs_bf,
              const float* __restrict__ fc_p_w, bf16u* __restrict__ fcp_bf,
              const float* __restrict__ whh, bf16u* __restrict__ wpack)
{
  int i = blockIdx.x * 256 + threadIdx.x;
  if (i < 3211264) { w_ih_bf[i] = f2b(w_ih[i]); return; }
  if (i < 5308416) { int j = i - 3211264; image_bf[j] = f2b(image[j]); return; }
  if (i < 5832704) { int j = i - 5308416; fcw_bf[j] = f2b(fc_w[j]); return; }
  if (i < 6094848) { int j = i - 5832704; fcv_bf[j] = f2b(fc_v_w[j]); return; }
  if (i < 6356992) { int j = i - 6094848; fchh_bf[j] = f2b(fc_hh_w[j]); return; }
  if (i < 6619136) { int j = i - 6356992; fcs_bf[j] = f2b(fc_s_w[j]); return; }
  if (i < 21979136) { int j = i - 6619136; fcp_bf[j] = f2b(fc_p_w[j]); return; }
  {
    // pack w_hh [2048][512] -> wpack[blk][kg][rr][8]
    int idx = i - 21979136;   // < 1048576
    int gr = idx >> 9, k = idx & 511;
    int gate = gr >> 9, win = gr & 511;
    int blk = win >> 4, lc = win & 15;
    int rr = gate * 16 + lc;
    wpack[(size_t)blk * 32768 + (((k >> 3) * 64 + rr) << 3) + (k & 7)] =
        f2b(whh[(size_t)gr * 512 + k]);
  }
}

// ---------------------------------------------------------------------------
// MFMA GEMM (m97 pattern): C[m,n] = act( A[m,:].W[n,:] + bias1 (+bias2) )
// A: M x K bf16 (lda), W: N x K bf16 (ldw).  128x128 tile, BK=32, 2x2 waves.
// MODE 1: vocab epilogue, grid (235,16).  OPERAND-SWAPPED MFMA
//   (mfma(W,A)) so each thread holds 4 CONSECUTIVE vocab cols per acc reg
//   quad -> float4 logit stores + register-local softmax stats.
//   (R5 lesson: XCD read-swizzle slowed this kernel — write locality rules.)
// MODE 2: bf16 store to C, 2-D grid (x = n-tile, y = m-tile).
// ---------------------------------------------------------------------------
#define BK 32
#define LDT 40

template<int MODE>
__global__ __launch_bounds__(256)
void gemm_bt(const bf16u* __restrict__ A, int lda,
             const bf16u* __restrict__ W, int ldw,
             const float* __restrict__ bias1, const float* __restrict__ bias2,
             bf16u* __restrict__ C, int ldc,
             int M, int N, int K, int act,
             const float* __restrict__ temp,
             float* __restrict__ outbase,
             float* __restrict__ pmax, float* __restrict__ psum)
{
  __shared__ __align__(16) bf16u As[128 * LDT];
  __shared__ __align__(16) bf16u Ws[128 * LDT];
  const int tid = threadIdx.x;
  const int n0 = blockIdx.x * 128;
  const int m0 = blockIdx.y * 128;
  const int wave = tid >> 6, lane = tid & 63;
  const int wm = wave >> 1, wn = wave & 1;
  const int q = lane >> 4, l16 = lane & 15;
  const int r0 = tid >> 2, s0 = tid & 3;

  const floatx4 zero = {0.f, 0.f, 0.f, 0.f};
  floatx4 acc[4][4];
#pragma unroll
  for (int i = 0; i < 4; ++i)
#pragma unroll
    for (int j = 0; j < 4; ++j) acc[i][j] = zero;

  int ar0 = m0 + r0;      if (ar0 >= M) ar0 = M - 1;
  int ar1 = m0 + r0 + 64; if (ar1 >= M) ar1 = M - 1;
  int wr0 = n0 + r0;      if (wr0 >= N) wr0 = N - 1;
  int wr1 = n0 + r0 + 64; if (wr1 >= N) wr1 = N - 1;
  const bf16u* Ap0 = A + (size_t)ar0 * lda + s0 * 8;
  const bf16u* Ap1 = A + (size_t)ar1 * lda + s0 * 8;
  const bf16u* Wp0 = W + (size_t)wr0 * ldw + s0 * 8;
  const bf16u* Wp1 = W + (size_t)wr1 * ldw + s0 * 8;

  for (int k0 = 0; k0 < K; k0 += BK) {
    const int4 a0 = *(const int4*)(Ap0 + k0);
    const int4 a1 = *(const int4*)(Ap1 + k0);
    const int4 w0 = *(const int4*)(Wp0 + k0);
    const int4 w1 = *(const int4*)(Wp1 + k0);
    __syncthreads();
    *(int4*)(As + r0 * LDT + s0 * 8) = a0;
    *(int4*)(As + (r0 + 64) * LDT + s0 * 8) = a1;
    *(int4*)(Ws + r0 * LDT + s0 * 8) = w0;
    *(int4*)(Ws + (r0 + 64) * LDT + s0 * 8) = w1;
    __syncthreads();
    short8 af[4], wf[4];
#pragma unroll
    for (int i = 0; i < 4; ++i) {
      af[i] = *(const short8*)(As + (wm * 64 + i * 16 + l16) * LDT + q * 8);
      wf[i] = *(const short8*)(Ws + (wn * 64 + i * 16 + l16) * LDT + q * 8);
    }
    if (MODE == 1) {
      // swapped: i = vocab (W) tile, j = batch (A) tile
#pragma unroll
      for (int i = 0; i < 4; ++i)
#pragma unroll
        for (int j = 0; j < 4; ++j)
          acc[i][j] = __builtin_amdgcn_mfma_f32_16x16x32_bf16(wf[i], af[j], acc[i][j], 0, 0, 0);
    } else {
#pragma unroll
      for (int i = 0; i < 4; ++i)
#pragma unroll
        for (int j = 0; j < 4; ++j)
          acc[i][j] = __builtin_amdgcn_mfma_f32_16x16x32_bf16(af[i], wf[j], acc[i][j], 0, 0, 0);
    }
  }

  if (MODE == 2) {
    // C/D layout: row(A) = (lane>>4)*4 + reg, col(W) = lane&15
    int colb[4]; float bias[4];
#pragma unroll
    for (int j = 0; j < 4; ++j) {
      int col = n0 + wn * 64 + j * 16 + l16;
      colb[j] = col;
      int cc = col < N ? col : N - 1;
      float bv = 0.f;
      if (bias1) bv += bias1[cc];
      if (bias2) bv += bias2[cc];
      bias[j] = bv;
    }
#pragma unroll
    for (int i = 0; i < 4; ++i) {
#pragma unroll
      for (int r = 0; r < 4; ++r) {
        int row = m0 + wm * 64 + i * 16 + q * 4 + r;
        if (row < M) {
#pragma unroll
          for (int j = 0; j < 4; ++j) {
            int col = colb[j];
            if (col < N) {
              float v = acc[i][j][r] + bias[j];
              if (act == 1) v = fmaxf(v, 0.f);
              C[(size_t)row * ldc + col] = f2b(v);
            }
          }
        }
      }
    }
  } else {
    // MODE 1 (swapped): vocab col = n0+wn*64+i*16+q*4+r (consecutive in r!),
    // out row = m0+wm*64+j*16+l16.  Lanes sharing a row: {l16, l16+16, +32, +48}.
    int pc = blockIdx.x * 2 + wn;   // 64-col slice index (< 470)
#pragma unroll
    for (int j = 0; j < 4; ++j) {
      int row = m0 + wm * 64 + j * 16 + l16;   // t*64 + b  (M=2048 exact)
      int bb = row & 63, tt = row >> 6;
      float rt = 1.0f / temp[bb];
      float4 ov[4];
      float mx = -1e30f;
#pragma unroll
      for (int i = 0; i < 4; ++i) {
        int col0 = n0 + wn * 64 + i * 16 + q * 4;   // multiple of 4; N%4==0
        bool ok = col0 < N;                          // all-or-none per quad
        float4 bv = ok ? *(const float4*)(bias1 + col0)
                       : make_float4(0.f, 0.f, 0.f, 0.f);
        floatx4 a = acc[i][j];
        float4 v;
        v.x = ok ? (a[0] + bv.x) * rt : -1e30f;
        v.y = ok ? (a[1] + bv.y) * rt : -1e30f;
        v.z = ok ? (a[2] + bv.z) * rt : -1e30f;
        v.w = ok ? (a[3] + bv.w) * rt : -1e30f;
        ov[i] = v;
        mx = fmaxf(mx, fmaxf(fmaxf(v.x, v.y), fmaxf(v.z, v.w)));
        if (ok)
          *(float4*)(outbase + (size_t)bb * 960000 + (size_t)tt * 30000 + col0) = v;
      }
      mx = fmaxf(mx, __shfl_xor(mx, 16));
      mx = fmaxf(mx, __shfl_xor(mx, 32));
      float s = 0.f;
#pragma unroll
      for (int i = 0; i < 4; ++i) {
        float4 v = ov[i];
        s += (v.x > -1e29f) ? __expf(v.x - mx) : 0.f;
        s += (v.y > -1e29f) ? __expf(v.y - mx) : 0.f;
        s += (v.z > -1e29f) ? __expf(v.z - mx) : 0.f;
        s += (v.w > -1e29f) ? __expf(v.w - mx) : 0.f;
      }
      s += __shfl_xor(s, 16);
      s += __shfl_xor(s, 32);
      if (q == 0) {
        pmax[(size_t)row * 470 + pc] = mx;
        psum[(size_t)row * 470 + pc] = s;
      }
    }
  }
}

// ---------------------------------------------------------------------------
// fused h0 + m0 scalar f32 GEMM (M=64, N=512, K=512, tanh), grid (2,2,2)
// ---------------------------------------------------------------------------
__global__ __launch_bounds__(256)
void gemm_hm(const float* __restrict__ A,
             const float* __restrict__ Wh, const float* __restrict__ bh,
             float* __restrict__ Ch,
             const float* __restrict__ Wm, const float* __restrict__ bm,
             float* __restrict__ Cm)
{
  __shared__ float Ash[512 * 36];
  const float* W = blockIdx.z ? Wm : Wh;
  const float* bias = blockIdx.z ? bm : bh;
  float* C = blockIdx.z ? Cm : Ch;
  const int tid = threadIdx.x;
  const int m0 = blockIdx.y * 32;
  const int n0 = blockIdx.x * 256;
  for (int idx = tid; idx < 32 * 512; idx += 256) {
    int r = idx >> 9, k = idx & 511;
    Ash[k * 36 + r] = A[(size_t)(m0 + r) * 512 + k];
  }
  __syncthreads();
  int n = n0 + tid;
  float acc[32];
#pragma unroll
  for (int r = 0; r < 32; ++r) acc[r] = 0.f;
  const float* wr = W + (size_t)n * 512;
  for (int k = 0; k < 512; ++k) {
    float w = wr[k];
    const float* a = Ash + (size_t)k * 36;
#pragma unroll
    for (int r = 0; r < 32; ++r) acc[r] += w * a[r];
  }
  float bv = bias[n];
#pragma unroll
  for (int r = 0; r < 32; ++r)
    C[(size_t)(m0 + r) * 512 + n] = tanhf(acc[r] + bv);
}

// ---------------------------------------------------------------------------
// init LSTM state: pack h0 (f32) into packed bf16 layout, copy m0 f32
// packed pos for h[b][jj]: ((jj>>3)*64 + b)*8 + (jj&7)
// ---------------------------------------------------------------------------
__global__ __launch_bounds__(256)
void init_state(const float* __restrict__ h0b, const float* __restrict__ m0b,
                bf16u* __restrict__ hOut, float* __restrict__ mbuf)
{
  int i = blockIdx.x * 256 + threadIdx.x;   // 32768
  int b = i >> 9, jj = i & 511;
  hOut[(((jj >> 3) * 64 + b) << 3) + (jj & 7)] = f2b(h0b[i]);
  mbuf[i] = m0b[i];
}

// ---------------------------------------------------------------------------
// LSTM timestep (launched 32x): 32 blocks, block owns 16 h-cols (64 gate rows).
// LDS: h packed (64KB) + weight slice packed (64KB) + gates f32 (16.6KB).
// gates[b][rr] = h@wslice^T via MFMA; pointwise -> hOut (packed), h_all, mbuf.
// (R4 lesson: persistent+grid-barrier variant = 9.25us/step > chain's ~6.7.)
// ---------------------------------------------------------------------------
__global__ __launch_bounds__(256)
void lstm_step(const bf16u* __restrict__ wpack, const bf16u* __restrict__ gx,
               const bf16u* __restrict__ hIn, bf16u* __restrict__ hOut,
               float* __restrict__ mbuf, bf16u* __restrict__ h_all, int t)
{
  extern __shared__ __align__(16) char smem[];
  bf16u* hsh = (bf16u*)smem;                 // 32768 bf16, [kg][b][8]
  bf16u* wsh = (bf16u*)(smem + 65536);       // 32768 bf16, [kg][rr][8]
  float* gsh = (float*)(smem + 131072);      // [64][65]
  const int blk = blockIdx.x, tid = threadIdx.x;

  const int4* hsrc = (const int4*)hIn;
  const int4* wsrc = (const int4*)(wpack + (size_t)blk * 32768);
  int4* hdst = (int4*)hsh; int4* wdst = (int4*)wsh;
#pragma unroll
  for (int u = 0; u < 16; ++u) {             // 4096 int4 each
    hdst[tid + 256 * u] = hsrc[tid + 256 * u];
    wdst[tid + 256 * u] = wsrc[tid + 256 * u];
  }
  __syncthreads();

  const int wave = tid >> 6, lane = tid & 63;
  const int wm = wave >> 1, wn = wave & 1, q = lane >> 4, l16 = lane & 15;
  const floatx4 zero = {0.f, 0.f, 0.f, 0.f};
  floatx4 acc[2][2];
#pragma unroll
  for (int i = 0; i < 2; ++i)
#pragma unroll
    for (int j = 0; j < 2; ++j) acc[i][j] = zero;

  for (int s = 0; s < 16; ++s) {
    short8 af[2], wf[2];
#pragma unroll
    for (int i = 0; i < 2; ++i)
      af[i] = *(const short8*)(hsh + ((((s * 4 + q) * 64) + wm * 32 + i * 16 + l16) << 3));
#pragma unroll
    for (int j = 0; j < 2; ++j)
      wf[j] = *(const short8*)(wsh + ((((s * 4 + q) * 64) + wn * 32 + j * 16 + l16) << 3));
#pragma unroll
    for (int i = 0; i < 2; ++i)
#pragma unroll
      for (int j = 0; j < 2; ++j)
        acc[i][j] = __builtin_amdgcn_mfma_f32_16x16x32_bf16(af[i], wf[j], acc[i][j], 0, 0, 0);
  }
  // D: col(rr) = lane&15 (+tile), row(b) = q*4+reg (+tile)
#pragma unroll
  for (int i = 0; i < 2; ++i)
#pragma unroll
    for (int j = 0; j < 2; ++j)
#pragma unroll
      for (int r = 0; r < 4; ++r)
        gsh[(wn * 32 + j * 16 + l16) * 65 + (wm * 32 + i * 16 + q * 4 + r)] = acc[i][j][r];
  __syncthreads();

#pragma unroll
  for (int u = 0; u < 4; ++u) {
    int p = tid + 256 * u;            // 1024 pairs
    int b = p >> 4, lc = p & 15;
    int jj = blk * 16 + lc;
    const bf16u* gxr = gx + ((size_t)t * 64 + b) * 2048;
    float ai = gsh[(lc) * 65 + b]        + b2f(gxr[jj]);
    float af = gsh[(16 + lc) * 65 + b]   + b2f(gxr[512 + jj]);
    float ag = gsh[(32 + lc) * 65 + b]   + b2f(gxr[1024 + jj]);
    float ao = gsh[(48 + lc) * 65 + b]   + b2f(gxr[1536 + jj]);
    float iv = fsigm(ai);
    float fv = fsigm(af);
    float gv = ftanh(ag);
    float ov = fsigm(ao);
    float mm = fv * mbuf[b * 512 + jj] + iv * gv;
    float hn = ov * ftanh(mm);
    mbuf[b * 512 + jj] = mm;
    bf16u hb = f2b(hn);
    hOut[(((jj >> 3) * 64 + b) << 3) + (jj & 7)] = hb;
    h_all[((size_t)t * 64 + b) * 512 + jj] = hb;
  }
}

// ---------------------------------------------------------------------------
// attention per (t,b) row — wave w owns k-quarter, lane l owns p = l.
// ---------------------------------------------------------------------------
__global__ __launch_bounds__(256)
void attn_kernel(const bf16u* __restrict__ vbuf, const float* __restrict__ image,
                 const bf16u* __restrict__ hs_bf, const bf16u* __restrict__ hh2,
                 const bf16u* __restrict__ s2, const float* __restrict__ wz,
                 const float* __restrict__ zb, float* __restrict__ attn_out,
                 bf16u* __restrict__ ctx)
{
  const int rown = blockIdx.x;            // t*64 + b
  const int bb = rown & 63, tt = rown >> 6;
  const int tid = threadIdx.x;
  const int wave = tid >> 6, lane = tid & 63;

  __shared__ float2 hwz[512];        // (hh, wz) per k
  __shared__ float zpart[64][4];     // per-p per-wave z partials
  __shared__ float spart[4];         // s-row per-wave partials
  __shared__ float ash[66];
  __shared__ float4 cpart[128];

  float sv0, sv1;
  {
    unsigned hr = *(const unsigned*)(hh2 + (size_t)rown * 512 + tid * 2);
    unsigned sr = *(const unsigned*)(s2 + (size_t)rown * 512 + tid * 2);
    float2 w2 = *(const float2*)(wz + tid * 2);
    hwz[tid * 2]     = make_float2(b2f((bf16u)(hr & 0xffffu)), w2.x);
    hwz[tid * 2 + 1] = make_float2(b2f((bf16u)(hr >> 16)), w2.y);
    sv0 = b2f((bf16u)(sr & 0xffffu));
    sv1 = b2f((bf16u)(sr >> 16));
  }
  __syncthreads();

  {
    const bf16u* vrow = vbuf + (size_t)(bb * 64 + lane) * 512 + wave * 128;
    float acc = 0.f;
    for (int c = 0; c < 16; ++c) {
      short8 vv = *(const short8*)(vrow + c * 8);
#pragma unroll
      for (int e = 0; e < 8; ++e) {
        float2 hz = hwz[wave * 128 + c * 8 + e];   // wave-uniform -> broadcast
        float tn = ftanh(b2f((bf16u)vv[e]) + hz.x);
        acc = __builtin_fmaf(tn, hz.y, acc);
      }
    }
    zpart[lane][wave] = acc;
  }

  {
    float2 h0 = hwz[tid * 2], h1 = hwz[tid * 2 + 1];
    float sacc = ftanh(sv0 + h0.x) * h0.y + ftanh(sv1 + h1.x) * h1.y;
#pragma unroll
    for (int off = 1; off < 64; off <<= 1) sacc += __shfl_xor(sacc, off);
    if (lane == 0) spart[wave] = sacc;
  }
  __syncthreads();

  if (wave == 0) {
    float zbv = zb[0];
    float4 zp = *(const float4*)zpart[lane];
    float z = zp.x + zp.y + zp.z + zp.w + zbv;
    float zs = spart[0] + spart[1] + spart[2] + spart[3] + zbv;
    float m = fmaxf(z, zs);
#pragma unroll
    for (int off = 1; off < 64; off <<= 1) m = fmaxf(m, __shfl_xor(m, off));
    float ez = __expf(z - m);
    float es = __expf(zs - m);
    float ssum = ez + (lane == 0 ? es : 0.f);
#pragma unroll
    for (int off = 1; off < 64; off <<= 1) ssum += __shfl_xor(ssum, off);
    float inv = 1.0f / ssum;
    ash[lane] = ez * inv;
    if (lane == 0) ash[64] = es * inv;
  }
  __syncthreads();

  size_t aoff = (size_t)bb * 2080 + (size_t)tt * 65;
  if (tid < 65) attn_out[aoff + tid] = ash[tid];

  const int e4 = tid & 127;          // float4 chunk
  const int ph = tid >> 7;           // p half (0: p<32, 1: p>=32)
  float4 cacc = {0.f, 0.f, 0.f, 0.f};
  const float* img = image + ((size_t)bb * 64 + (size_t)ph * 32) * 512 + e4 * 4;
  for (int p = 0; p < 32; ++p) {
    float a = ash[ph * 32 + p];
    float4 iv = *(const float4*)(img + (size_t)p * 512);
    cacc.x = __builtin_fmaf(a, iv.x, cacc.x);
    cacc.y = __builtin_fmaf(a, iv.y, cacc.y);
    cacc.z = __builtin_fmaf(a, iv.z, cacc.z);
    cacc.w = __builtin_fmaf(a, iv.w, cacc.w);
  }
  if (ph == 1) cpart[e4] = cacc;
  __syncthreads();
  if (ph == 0) {
    float4 o = cpart[e4];
    cacc.x += o.x; cacc.y += o.y; cacc.z += o.z; cacc.w += o.w;
    const bf16u* hsrow = hs_bf + (size_t)rown * 1024;
    int2 hraw = *(const int2*)(hsrow + e4 * 4);          // hh raw (4 bf16)
    int2 sraw = *(const int2*)(hsrow + 512 + e4 * 4);    // s raw (4 bf16)
    float a64 = ash[64];
    cacc.x += a64 * b2f((bf16u)(sraw.x & 0xffff)) + b2f((bf16u)(hraw.x & 0xffff));
    cacc.y += a64 * b2f((bf16u)((unsigned)sraw.x >> 16)) + b2f((bf16u)((unsigned)hraw.x >> 16));
    cacc.z += a64 * b2f((bf16u)(sraw.y & 0xffff)) + b2f((bf16u)(hraw.y & 0xffff));
    cacc.w += a64 * b2f((bf16u)((unsigned)sraw.y >> 16)) + b2f((bf16u)((unsigned)hraw.y >> 16));
    unsigned o0 = (unsigned)f2b(cacc.x) | ((unsigned)f2b(cacc.y) << 16);
    unsigned o1 = (unsigned)f2b(cacc.z) | ((unsigned)f2b(cacc.w) << 16);
    *(int2*)(ctx + (size_t)rown * 512 + e4 * 4) = make_int2((int)o0, (int)o1);
  }
}

// ---------------------------------------------------------------------------
// combine per-64col partials -> lse & rowmax.  One wave per row.
// ---------------------------------------------------------------------------
__global__ __launch_bounds__(256)
void reduce_lse(const float* __restrict__ pmax, const float* __restrict__ psum,
                float* __restrict__ lse, float* __restrict__ rmax)
{
  int row = blockIdx.x * 4 + (threadIdx.x >> 6);   // 4 waves/block, 512 blocks
  int lane = threadIdx.x & 63;
  const float* pm = pmax + (size_t)row * 470;
  const float* ps = psum + (size_t)row * 470;
  float m = -1e30f, s = 0.f;
  for (int c = lane; c < 470; c += 64) {
    float mi = pm[c];
    float si = ps[c];
    if (mi > m) { s = s * __expf(m - mi) + si; m = mi; }
    else        { s += si * __expf(mi - m); }
  }
#pragma unroll
  for (int off = 1; off < 64; off <<= 1) {
    float mo = __shfl_xor(m, off);
    float so = __shfl_xor(s, off);
    float mn = fmaxf(m, mo);
    s = s * __expf(m - mn) + so * __expf(mo - mn);
    m = mn;
  }
  if (lane == 0) {
    rmax[row] = m;
    lse[row] = m + logf(s);
  }
}

// ---------------------------------------------------------------------------
// logp = logit - lse (in place, float4).  out row rflat = b*32+t.
// ---------------------------------------------------------------------------
__global__ __launch_bounds__(256)
void finalize_kernel(float* __restrict__ out, const float* __restrict__ lse)
{
  int idx = blockIdx.x * 256 + threadIdx.x;   // 15,360,000 float4s
  if (idx >= 15360000) return;
  int rflat = idx / 7500;
  int c4 = idx - rflat * 7500;
  float L = lse[(rflat & 31) * 64 + (rflat >> 5)];
  float4* p = (float4*)(out + (size_t)rflat * 30000 + (size_t)c4 * 4);
  float4 v = *p;
  v.x -= L; v.y -= L; v.z -= L; v.w -= L;
  *p = v;
}

__global__ void slp_kernel(const float* __restrict__ rmax,
                           const float* __restrict__ lse, float* __restrict__ out)
{
  int b = threadIdx.x;              // 64 threads
  float s = 0.f;
  for (int t = 0; t < 32; ++t) { int r = t * 64 + b; s += rmax[r] - lse[r]; }
  out[61440000 + 133120 + b] = s;
}

// ---------------------------------------------------------------------------
extern "C" void kernel_launch(void* const* d_in, const int* in_sizes, int n_in,
                              void* d_out, int out_size, void* d_ws, size_t ws_size,
                              hipStream_t stream)
{
  const float* image   = (const float*)d_in[0];
  const float* vp      = (const float*)d_in[1];
  const float* lab     = (const float*)d_in[2];
  const float* topic   = (const float*)d_in[3];
  const float* temp    = (const float*)d_in[4];
  const int*   text    = (const int*)d_in[5];
  const float* wemb    = (const float*)d_in[6];
  const float* fc_v_w  = (const float*)d_in[7];
  const float* fc_v_b  = (const float*)d_in[8];
  const float* fc_h_w  = (const float*)d_in[9];
  const float* fc_h_b  = (const float*)d_in[10];
  const float* fc_m_w  = (const float*)d_in[11];
  const float* fc_m_b  = (const float*)d_in[12];
  const float* w_ih    = (const float*)d_in[13];
  const float* w_hh    = (const float*)d_in[14];
  const float* b_ih    = (const float*)d_in[15];
  const float* b_hh    = (const float*)d_in[16];
  const float* fc_w    = (const float*)d_in[17];
  const float* fc_b    = (const float*)d_in[18];
  const float* fc_hh_w = (const float*)d_in[19];
  const float* fc_hh_b = (const float*)d_in[20];
  const float* fc_s_w  = (const float*)d_in[21];
  const float* fc_s_b  = (const float*)d_in[22];
  const float* fc_z_w  = (const float*)d_in[23];
  const float* fc_z_b  = (const float*)d_in[24];
  const float* fc_p_w  = (const float*)d_in[25];
  const float* fc_p_b  = (const float*)d_in[26];
  float* out = (float*)d_out;

  char* base = (char*)d_ws;
  size_t off = 0;
  auto alloc = [&](size_t bytes) -> char* {
    char* p = base + off;
    off += (bytes + 255) & ~(size_t)255;
    return p;
  };
  bf16u* X       = (bf16u*)alloc(2048ull * 1568 * 2);   // dead after gates gemm
  bf16u* w_ih_bf = (bf16u*)alloc(2048ull * 1568 * 2);   // dead after gates gemm
  bf16u* gx_bf   = (bf16u*)alloc(2048ull * 2048 * 2);   // dead after lstm
  bf16u* image_bf= (bf16u*)alloc(4096ull * 512 * 2);    // dead after v gemm
  bf16u* wpackb  = (bf16u*)alloc(2048ull * 512 * 2);
  bf16u* fcv_bf  = (bf16u*)alloc(512ull * 512 * 2);
  bf16u* fcw_bf  = (bf16u*)alloc(1024ull * 512 * 2);
  bf16u* fchh_bf = (bf16u*)alloc(512ull * 512 * 2);
  bf16u* fcs_bf  = (bf16u*)alloc(512ull * 512 * 2);
  bf16u* fcp_bf  = (bf16u*)alloc(30000ull * 512 * 2);
  float* imean   = (float*)alloc(64ull * 512 * 4);
  float* h0b     = (float*)alloc(64ull * 512 * 4);
  float* m0b     = (float*)alloc(64ull * 512 * 4);
  bf16u* vbuf    = (bf16u*)alloc(4096ull * 512 * 2);
  bf16u* hA      = (bf16u*)alloc(64ull * 512 * 2);
  bf16u* hB      = (bf16u*)alloc(64ull * 512 * 2);
  float* mbuf    = (float*)alloc(64ull * 512 * 4);
  bf16u* h_all   = (bf16u*)alloc(2048ull * 512 * 2);
  float* rmaxb   = (float*)alloc(2048ull * 4);
  float* lseb    = (float*)alloc(2048ull * 4);
  // overlays (regions dead by the time these are written):
  bf16u* hs_bf   = (bf16u*)w_ih_bf;                     // 2048x1024 bf16 (4.2MB <= 6.4MB)
  bf16u* ctx     = (bf16u*)(w_ih_bf + 2048ull * 1024);  // 2048x512 bf16 (fits)
  bf16u* hhbuf   = (bf16u*)X;                           // 2048x512 bf16
  bf16u* sbuf    = (bf16u*)(X + 2048ull * 512);         // 2048x512 bf16 (fits in X)
  float* pmaxb   = (float*)gx_bf;                       // 2048x470 f32
  float* psumb   = (float*)(gx_bf + 2048ull * 2048);    // second half of gx region
  (void)in_sizes; (void)n_in; (void)out_size; (void)ws_size;

  // --- prep & conversions (fused) ---
  mean_prep<<<64, 256, 0, stream>>>(image, vp, lab, topic, text, wemb, imean, X);
  mega_cvt<<<89952, 256, 0, stream>>>(w_ih, w_ih_bf, image, image_bf,
                                      fc_w, fcw_bf, fc_v_w, fcv_bf,
                                      fc_hh_w, fchh_bf, fc_s_w, fcs_bf,
                                      fc_p_w, fcp_bf, w_hh, wpackb);

  // gates_x = X @ w_ih^T + b_ih + b_hh  (2048x2048x1568) -> bf16
  gemm_bt<2><<<dim3(16, 16), 256, 0, stream>>>(X, 1568, w_ih_bf, 1568, b_ih, b_hh,
      gx_bf, 2048, 2048, 2048, 1568, 0, nullptr, nullptr, nullptr, nullptr);
  // v = image @ fc_v_w^T + b  (4096x512x512) -> bf16
  gemm_bt<2><<<dim3(4, 32), 256, 0, stream>>>(image_bf, 512, fcv_bf, 512, fc_v_b, nullptr,
      vbuf, 512, 4096, 512, 512, 0, nullptr, nullptr, nullptr, nullptr);
  // h0 + m0 fused (tiny f32)
  gemm_hm<<<dim3(2, 2, 2), 256, 0, stream>>>(imean, fc_h_w, fc_h_b, h0b,
                                             fc_m_w, fc_m_b, m0b);

  // --- LSTM: 32 per-timestep MFMA launches ---
  init_state<<<128, 256, 0, stream>>>(h0b, m0b, hA, mbuf);
  const int lstm_lds = 65536 + 65536 + 64 * 65 * 4;   // 147,712 B
  for (int t = 0; t < 32; ++t) {
    const bf16u* hi = (t & 1) ? hB : hA;
    bf16u* ho = (t & 1) ? hA : hB;
    lstm_step<<<32, 256, lstm_lds, stream>>>(wpackb, gx_bf, hi, ho, mbuf, h_all, t);
  }

  // hs = relu(h_all @ fc_w^T + b)  (2048x1024x512) -> bf16
  gemm_bt<2><<<dim3(8, 16), 256, 0, stream>>>(h_all, 512, fcw_bf, 512, fc_b, nullptr,
      hs_bf, 1024, 2048, 1024, 512, 1, nullptr, nullptr, nullptr, nullptr);
  // _hh / _s  (2048x512x512) -> bf16
  gemm_bt<2><<<dim3(4, 16), 256, 0, stream>>>(hs_bf, 1024, fchh_bf, 512, fc_hh_b, nullptr,
      hhbuf, 512, 2048, 512, 512, 0, nullptr, nullptr, nullptr, nullptr);
  gemm_bt<2><<<dim3(4, 16), 256, 0, stream>>>(hs_bf + 512, 1024, fcs_bf, 512, fc_s_b, nullptr,
      sbuf, 512, 2048, 512, 512, 0, nullptr, nullptr, nullptr, nullptr);

  attn_kernel<<<2048, 256, 0, stream>>>(vbuf, image, hs_bf, hhbuf, sbuf,
      fc_z_w, fc_z_b, out + 61440000, ctx);

  // vocab projection + fused softmax stats (2048x30000x512), 2-D grid
  gemm_bt<1><<<dim3(235, 16), 256, 0, stream>>>(ctx, 512, fcp_bf, 512, fc_p_b, nullptr,
      nullptr, 0, 2048, 30000, 512, 0, temp, out, pmaxb, psumb);

  reduce_lse<<<512, 256, 0, stream>>>(pmaxb, psumb, lseb, rmaxb);
  finalize_kernel<<<60000, 256, 0, stream>>>(out, lseb);
  slp_kernel<<<1, 64, 0, stream>>>(rmaxb, lseb, out);
}